// Round 4
// baseline (1717.908 us; speedup 1.0000x reference)
//
#include <hip/hip_runtime.h>
#include <hip/hip_bf16.h>

typedef __attribute__((ext_vector_type(8))) short short8;
typedef __attribute__((ext_vector_type(4))) float f32x4;
typedef __attribute__((ext_vector_type(4))) float float4v;

static __device__ __forceinline__ unsigned short f2bf(float f) {
    union { float f; unsigned u; } v; v.f = f;
    unsigned r = v.u + 0x7fff + ((v.u >> 16) & 1);   // round-to-nearest-even
    return (unsigned short)(r >> 16);
}

// ---------------- transpose + f32->bf16 convert: out[c][r] = bf16(in[r][c]) --
__global__ __launch_bounds__(256) void transpose_bf16(
    const float* __restrict__ in, unsigned short* __restrict__ out, int R, int Cc)
{
    __shared__ float tile[32][33];
    int c0 = blockIdx.x * 32, r0 = blockIdx.y * 32;
    int tx = threadIdx.x, ty = threadIdx.y;      // 32 x 8
#pragma unroll
    for (int i = 0; i < 32; i += 8) {
        int r = r0 + ty + i, c = c0 + tx;
        tile[ty + i][tx] = (r < R && c < Cc) ? in[(size_t)r * Cc + c] : 0.f;
    }
    __syncthreads();
#pragma unroll
    for (int i = 0; i < 32; i += 8) {
        int c = c0 + ty + i, r = r0 + tx;        // out[c][r]
        if (c < Cc && r < R) out[(size_t)c * R + r] = f2bf(tile[tx][ty + i]);
    }
}

// ---------------- MFMA GEMM: C = A @ Bt^T + bias, optional softplus ----------
// A: f32 [M][lda] (converted to bf16 during staging). Bt: bf16 [N][ldb].
// Tile 128x128, BK=32. 4 waves, each owns a 64x64 quadrant (4x4 MFMA frags).
// K must be a multiple of 32. M/N guarded.
template <int ACT>
__global__ __launch_bounds__(256) void gemm_mfma(
    const float* __restrict__ A, int lda,
    const unsigned short* __restrict__ Bt, int ldb,
    const float* __restrict__ bias,
    float* __restrict__ C, int ldc,
    int M, int N, int K)
{
    __shared__ unsigned short As[128 * 32];
    __shared__ unsigned short Bs[128 * 32];

    const int tid  = threadIdx.x;
    const int lane = tid & 63;
    const int wave = tid >> 6;
    const int g    = lane >> 4;        // k-group 0..3
    const int r16  = lane & 15;
    const int wr   = (wave >> 1) * 64; // wave row offset in tile
    const int wc   = (wave & 1) * 64;  // wave col offset in tile
    const int rowBase = blockIdx.y * 128;
    const int colBase = blockIdx.x * 128;

    f32x4 acc[4][4] = {};

    for (int k0 = 0; k0 < K; k0 += 32) {
        // ---- stage A (f32 -> bf16): 128 rows x 32 k = 512 chunks of 8
#pragma unroll
        for (int c = 0; c < 2; ++c) {
            int chunk = c * 256 + tid;
            int r = chunk >> 2;            // tile row
            int slot = chunk & 3;          // 8-element k slot
            int gr = rowBase + r;
            short8 t = {};
            if (gr < M) {
                const float* src = A + (size_t)gr * lda + k0 + slot * 8;
                float4v v0 = *reinterpret_cast<const float4v*>(src);
                float4v v1 = *reinterpret_cast<const float4v*>(src + 4);
                t[0] = (short)f2bf(v0[0]); t[1] = (short)f2bf(v0[1]);
                t[2] = (short)f2bf(v0[2]); t[3] = (short)f2bf(v0[3]);
                t[4] = (short)f2bf(v1[0]); t[5] = (short)f2bf(v1[1]);
                t[6] = (short)f2bf(v1[2]); t[7] = (short)f2bf(v1[3]);
            }
            int sslot = slot ^ (r & 3);    // XOR swizzle (both sides)
            *reinterpret_cast<short8*>(&As[r * 32 + sslot * 8]) = t;
        }
        // ---- stage Bt (already bf16): 128 rows(=out cols) x 32 k
#pragma unroll
        for (int c = 0; c < 2; ++c) {
            int chunk = c * 256 + tid;
            int r = chunk >> 2;
            int slot = chunk & 3;
            int gn = colBase + r;
            short8 t = {};
            if (gn < N)
                t = *reinterpret_cast<const short8*>(Bt + (size_t)gn * ldb + k0 + slot * 8);
            int sslot = slot ^ (r & 3);
            *reinterpret_cast<short8*>(&Bs[r * 32 + sslot * 8]) = t;
        }
        __syncthreads();

        // ---- fragments: lane reads 8 consecutive k (same mapping for A and B)
        short8 af[4], bfr[4];
#pragma unroll
        for (int m = 0; m < 4; ++m) {
            int r = wr + m * 16 + r16;
            int sslot = g ^ (r & 3);
            af[m] = *reinterpret_cast<const short8*>(&As[r * 32 + sslot * 8]);
        }
#pragma unroll
        for (int n = 0; n < 4; ++n) {
            int r = wc + n * 16 + r16;
            int sslot = g ^ (r & 3);
            bfr[n] = *reinterpret_cast<const short8*>(&Bs[r * 32 + sslot * 8]);
        }
#pragma unroll
        for (int m = 0; m < 4; ++m)
#pragma unroll
            for (int n = 0; n < 4; ++n)
                acc[m][n] = __builtin_amdgcn_mfma_f32_16x16x32_bf16(
                    af[m], bfr[n], acc[m][n], 0, 0, 0);
        __syncthreads();
    }

    // ---- epilogue: D row = g*4 + v (A-side), col = r16 (B-side)  [m89/m91]
#pragma unroll
    for (int m = 0; m < 4; ++m) {
#pragma unroll
        for (int v = 0; v < 4; ++v) {
            int gr = rowBase + wr + m * 16 + g * 4 + v;
            if (gr >= M) continue;
#pragma unroll
            for (int n = 0; n < 4; ++n) {
                int gc = colBase + wc + n * 16 + r16;
                if (gc >= N) continue;
                float val = acc[m][n][v] + bias[gc];
                if (ACT == 1) val = (val > 20.f) ? val : log1pf(expf(val));
                C[(size_t)gr * ldc + gc] = val;
            }
        }
    }
}

// ---------------- depthwise causal conv (mean of 3) + SiLU -------------------
__global__ __launch_bounds__(256) void conv_silu(
    const float* __restrict__ xz, float* __restrict__ xconv)
{
    int idx = blockIdx.x * blockDim.x + threadIdx.x;
    if (idx >= 4096 * 2048) return;
    int d = idx & 2047;
    int row = idx >> 11;        // row = b*2048 + l
    int l = row & 2047;

    float s = xz[(size_t)row * 4096 + d];
    if (l >= 1) s += xz[(size_t)(row - 1) * 4096 + d];
    if (l >= 2) s += xz[(size_t)(row - 2) * 4096 + d];
    s *= (1.f / 3.f);
    float sv = s / (1.f + __expf(-s));
    xconv[idx] = sv;
}

// ---------------- selective scan (f32, fused skip + gate) --------------------
__global__ __launch_bounds__(256) void scan_kernel(
    const float* __restrict__ dt,     // [4096][2048]
    const float* __restrict__ xdbl,   // [4096][96]
    const float* __restrict__ xz,     // [4096][4096] (z at cols 2048..4095)
    float* __restrict__ xconv,        // [4096][2048] in: x_conv, out: gated
    const float* __restrict__ A_log,  // [2048][16]
    const float* __restrict__ Dp)     // [2048]
{
    const int L = 2048, DI = 2048;
    const int n = threadIdx.x & 15;
    const int chi = threadIdx.x >> 4;
    const int blocksPerBatch = DI / 16;       // 128
    const int b = blockIdx.x / blocksPerBatch;
    const int d = (blockIdx.x % blocksPerBatch) * 16 + chi;

    const float Aval = -expf(A_log[d * 16 + n]);
    const float Dval = Dp[d];
    float h = 0.f;
    const size_t rowBase = (size_t)b * L;

    float dt_c = dt[rowBase * DI + d];
    float x_c  = xconv[rowBase * DI + d];
    float B_c  = xdbl[rowBase * 96 + 64 + n];
    float C_c  = xdbl[rowBase * 96 + 80 + n];

    for (int t = 0; t < L; ++t) {
        size_t row = rowBase + t;
        float dt_n = 0.f, x_n = 0.f, B_n = 0.f, C_n = 0.f;
        if (t + 1 < L) {
            size_t rn = row + 1;
            dt_n = dt[rn * DI + d];
            x_n  = xconv[rn * DI + d];
            B_n  = xdbl[rn * 96 + 64 + n];
            C_n  = xdbl[rn * 96 + 80 + n];
        }

        float dA = __expf(Aval * dt_c);
        h = dA * h + (dt_c * x_c) * B_c;
        float p = h * C_c;
        p += __shfl_xor(p, 1, 16);
        p += __shfl_xor(p, 2, 16);
        p += __shfl_xor(p, 4, 16);
        p += __shfl_xor(p, 8, 16);

        if (n == 0) {
            float y = p + x_c * Dval;
            float zv = xz[row * 4096 + 2048 + d];
            float sz = zv / (1.f + __expf(-zv));
            xconv[row * DI + d] = y * sz;
        }

        dt_c = dt_n; x_c = x_n; B_c = B_n; C_c = C_n;
    }
}

extern "C" void kernel_launch(void* const* d_in, const int* in_sizes, int n_in,
                              void* d_out, int out_size, void* d_ws, size_t ws_size,
                              hipStream_t stream)
{
    const float* x     = (const float*)d_in[0];
    const float* W_in  = (const float*)d_in[1];
    const float* b_in  = (const float*)d_in[2];
    const float* W_x   = (const float*)d_in[3];
    const float* b_x   = (const float*)d_in[4];
    const float* W_dt  = (const float*)d_in[5];
    const float* b_dt  = (const float*)d_in[6];
    const float* A_log = (const float*)d_in[7];
    const float* Dp    = (const float*)d_in[8];
    const float* W_out = (const float*)d_in[9];
    const float* b_out = (const float*)d_in[10];
    float* out = (float*)d_out;

    float* ws    = (float*)d_ws;
    float* xz    = ws;                       // 16,777,216 f32
    float* xconv = xz + 16777216;            //  8,388,608 f32
    float* xdbl  = xconv + 8388608;          //    393,216 f32
    float* dtbuf = xdbl + 393216;            //  8,388,608 f32
    unsigned short* wbuf = (unsigned short*)(dtbuf + 8388608);
    unsigned short* WinT  = wbuf;                  // [4096][1024] bf16
    unsigned short* WxT   = WinT  + 4096 * 1024;   // [96][2048]
    unsigned short* WdtT  = WxT   + 96 * 2048;     // [2048][64]
    unsigned short* WoutT = WdtT  + 2048 * 64;     // [1024][2048]

    const size_t needed = (size_t)(16777216 + 8388608 + 393216 + 8388608) * 4
                        + (size_t)(4096 * 1024 + 96 * 2048 + 2048 * 64 + 1024 * 2048) * 2;
    if (ws_size < needed) return;   // tripwire: clean fail, never corrupt memory

    dim3 tblk(32, 8);
    // weight transposes + bf16 convert
    transpose_bf16<<<dim3(128, 32), tblk, 0, stream>>>(W_in, WinT, 1024, 4096);
    transpose_bf16<<<dim3(3, 64),   tblk, 0, stream>>>(W_x,  WxT,  2048, 96);
    transpose_bf16<<<dim3(64, 2),   tblk, 0, stream>>>(W_dt, WdtT, 64, 2048);
    transpose_bf16<<<dim3(32, 64),  tblk, 0, stream>>>(W_out,WoutT,2048, 1024);

    dim3 blk(256);

    // 1) xz = x @ W_in + b_in   (M=4096, N=4096, K=1024)
    gemm_mfma<0><<<dim3(32, 32), blk, 0, stream>>>(
        x, 1024, WinT, 1024, b_in, xz, 4096, 4096, 4096, 1024);

    // 2) x_conv = silu(causal mean3(x_inner))
    conv_silu<<<(4096 * 2048 + 255) / 256, blk, 0, stream>>>(xz, xconv);

    // 3) x_dbl = x_conv @ W_x + b_x   (M=4096, N=96, K=2048)
    gemm_mfma<0><<<dim3(1, 32), blk, 0, stream>>>(
        xconv, 2048, WxT, 2048, b_x, xdbl, 96, 4096, 96, 2048);

    // 4) dt = softplus(x_dbl[:, :64] @ W_dt + b_dt)   (M=4096, N=2048, K=64)
    gemm_mfma<1><<<dim3(16, 32), blk, 0, stream>>>(
        xdbl, 96, WdtT, 64, b_dt, dtbuf, 2048, 4096, 2048, 64);

    // 5) selective scan (+ skip, + gate) -> gated stored over xconv
    scan_kernel<<<256, blk, 0, stream>>>(dtbuf, xdbl, xz, xconv, A_log, Dp);

    // 6) out = gated @ W_out + b_out   (M=4096, N=1024, K=2048)
    gemm_mfma<0><<<dim3(8, 32), blk, 0, stream>>>(
        xconv, 2048, WoutT, 2048, b_out, out, 1024, 4096, 1024, 2048);
}

// Round 6
// 786.899 us; speedup vs baseline: 2.1831x; 2.1831x over previous
//
#include <hip/hip_runtime.h>
#include <hip/hip_bf16.h>

typedef __attribute__((ext_vector_type(8))) short short8;
typedef __attribute__((ext_vector_type(4))) float f32x4;
typedef __attribute__((ext_vector_type(4))) float float4v;

#define NCHUNK 16
#define CT 128   // chunk length (NCHUNK*CT == L == 2048)

static __device__ __forceinline__ unsigned short f2bf(float f) {
    union { float f; unsigned u; } v; v.f = f;
    unsigned r = v.u + 0x7fff + ((v.u >> 16) & 1);   // round-to-nearest-even
    return (unsigned short)(r >> 16);
}

// ---------------- transpose + f32->bf16 convert: out[c][r] = bf16(in[r][c]) --
__global__ __launch_bounds__(256) void transpose_bf16(
    const float* __restrict__ in, unsigned short* __restrict__ out, int R, int Cc)
{
    __shared__ float tile[32][33];
    int c0 = blockIdx.x * 32, r0 = blockIdx.y * 32;
    int tx = threadIdx.x, ty = threadIdx.y;      // 32 x 8
#pragma unroll
    for (int i = 0; i < 32; i += 8) {
        int r = r0 + ty + i, c = c0 + tx;
        tile[ty + i][tx] = (r < R && c < Cc) ? in[(size_t)r * Cc + c] : 0.f;
    }
    __syncthreads();
#pragma unroll
    for (int i = 0; i < 32; i += 8) {
        int c = c0 + ty + i, r = r0 + tx;        // out[c][r]
        if (c < Cc && r < R) out[(size_t)c * R + r] = f2bf(tile[tx][ty + i]);
    }
}

// ---------------- MFMA GEMM: C = A @ Bt^T + bias, optional softplus ----------
// A: f32 [M][lda] (converted to bf16 during staging). Bt: bf16 [N][ldb].
// Tile 128x128, BK=32. 4 waves, each owns a 64x64 quadrant (4x4 MFMA frags).
template <int ACT>
__global__ __launch_bounds__(256) void gemm_mfma(
    const float* __restrict__ A, int lda,
    const unsigned short* __restrict__ Bt, int ldb,
    const float* __restrict__ bias,
    float* __restrict__ C, int ldc,
    int M, int N, int K)
{
    __shared__ unsigned short As[128 * 32];
    __shared__ unsigned short Bs[128 * 32];

    const int tid  = threadIdx.x;
    const int lane = tid & 63;
    const int wave = tid >> 6;
    const int g    = lane >> 4;        // k-group 0..3
    const int r16  = lane & 15;
    const int wr   = (wave >> 1) * 64; // wave row offset in tile
    const int wc   = (wave & 1) * 64;  // wave col offset in tile
    const int rowBase = blockIdx.y * 128;
    const int colBase = blockIdx.x * 128;

    f32x4 acc[4][4] = {};

    for (int k0 = 0; k0 < K; k0 += 32) {
        // ---- stage A (f32 -> bf16): 128 rows x 32 k = 512 chunks of 8
#pragma unroll
        for (int c = 0; c < 2; ++c) {
            int chunk = c * 256 + tid;
            int r = chunk >> 2;            // tile row
            int slot = chunk & 3;          // 8-element k slot
            int gr = rowBase + r;
            short8 t = {};
            if (gr < M) {
                const float* src = A + (size_t)gr * lda + k0 + slot * 8;
                float4v v0 = *reinterpret_cast<const float4v*>(src);
                float4v v1 = *reinterpret_cast<const float4v*>(src + 4);
                t[0] = (short)f2bf(v0[0]); t[1] = (short)f2bf(v0[1]);
                t[2] = (short)f2bf(v0[2]); t[3] = (short)f2bf(v0[3]);
                t[4] = (short)f2bf(v1[0]); t[5] = (short)f2bf(v1[1]);
                t[6] = (short)f2bf(v1[2]); t[7] = (short)f2bf(v1[3]);
            }
            int sslot = slot ^ (r & 3);    // XOR swizzle (both sides)
            *reinterpret_cast<short8*>(&As[r * 32 + sslot * 8]) = t;
        }
        // ---- stage Bt (already bf16): 128 rows(=out cols) x 32 k
#pragma unroll
        for (int c = 0; c < 2; ++c) {
            int chunk = c * 256 + tid;
            int r = chunk >> 2;
            int slot = chunk & 3;
            int gn = colBase + r;
            short8 t = {};
            if (gn < N)
                t = *reinterpret_cast<const short8*>(Bt + (size_t)gn * ldb + k0 + slot * 8);
            int sslot = slot ^ (r & 3);
            *reinterpret_cast<short8*>(&Bs[r * 32 + sslot * 8]) = t;
        }
        __syncthreads();

        // ---- fragments: lane reads 8 consecutive k (same mapping for A and B)
        short8 af[4], bfr[4];
#pragma unroll
        for (int m = 0; m < 4; ++m) {
            int r = wr + m * 16 + r16;
            int sslot = g ^ (r & 3);
            af[m] = *reinterpret_cast<const short8*>(&As[r * 32 + sslot * 8]);
        }
#pragma unroll
        for (int n = 0; n < 4; ++n) {
            int r = wc + n * 16 + r16;
            int sslot = g ^ (r & 3);
            bfr[n] = *reinterpret_cast<const short8*>(&Bs[r * 32 + sslot * 8]);
        }
#pragma unroll
        for (int m = 0; m < 4; ++m)
#pragma unroll
            for (int n = 0; n < 4; ++n)
                acc[m][n] = __builtin_amdgcn_mfma_f32_16x16x32_bf16(
                    af[m], bfr[n], acc[m][n], 0, 0, 0);
        __syncthreads();
    }

    // ---- epilogue: D row = g*4 + v (A-side), col = r16 (B-side)  [m89/m91]
#pragma unroll
    for (int m = 0; m < 4; ++m) {
#pragma unroll
        for (int v = 0; v < 4; ++v) {
            int gr = rowBase + wr + m * 16 + g * 4 + v;
            if (gr >= M) continue;
#pragma unroll
            for (int n = 0; n < 4; ++n) {
                int gc = colBase + wc + n * 16 + r16;
                if (gc >= N) continue;
                float val = acc[m][n][v] + bias[gc];
                if (ACT == 1) val = (val > 20.f) ? val : log1pf(expf(val));
                C[(size_t)gr * ldc + gc] = val;
            }
        }
    }
}

// ---------------- depthwise causal conv (mean of 3) + SiLU -------------------
__global__ __launch_bounds__(256) void conv_silu(
    const float* __restrict__ xz, float* __restrict__ xconv)
{
    int idx = blockIdx.x * blockDim.x + threadIdx.x;
    if (idx >= 4096 * 2048) return;
    int d = idx & 2047;
    int row = idx >> 11;        // row = b*2048 + l
    int l = row & 2047;

    float s = xz[(size_t)row * 4096 + d];
    if (l >= 1) s += xz[(size_t)(row - 1) * 4096 + d];
    if (l >= 2) s += xz[(size_t)(row - 2) * 4096 + d];
    s *= (1.f / 3.f);
    float sv = s / (1.f + __expf(-s));
    xconv[idx] = sv;
}

// ---------------- chunked selective scan -------------------------------------
// h[t] = dA[t]*h[t-1] + u[t] is linear => two-level chunk decomposition.
// Lane = (chi=channel-in-group, n=state). Block = (b, chunk, d-group of 16).

// Pass A: per chunk, h_in = 0: P = prod(dA), S = local final state.
__global__ __launch_bounds__(256) void scan_passA(
    const float* __restrict__ dt,     // [4096][2048]
    const float* __restrict__ xdbl,   // [4096][96]
    const float* __restrict__ xconv,  // [4096][2048]
    const float* __restrict__ A_log,  // [2048][16]
    float* __restrict__ Pc,           // [2][16][2048][16]
    float* __restrict__ Sc)           // [2][16][2048][16]
{
    const int DI = 2048, L = 2048;
    const int n   = threadIdx.x & 15;
    const int chi = threadIdx.x >> 4;
    const int bid = blockIdx.x;          // 4096 = b(2) x c(16) x dg(128)
    const int dg  = bid & 127;
    const int c   = (bid >> 7) & 15;
    const int b   = bid >> 11;
    const int d   = dg * 16 + chi;

    const float Aval = -expf(A_log[d * 16 + n]);
    const size_t rowBase = (size_t)b * L + (size_t)c * CT;

    float P = 1.f, S = 0.f;
    float dt_c = dt[rowBase * DI + d];
    float x_c  = xconv[rowBase * DI + d];
    float B_c  = xdbl[rowBase * 96 + 64 + n];

    for (int t = 0; t < CT; ++t) {
        size_t row = rowBase + t;
        float dt_n = 0.f, x_n = 0.f, B_n = 0.f;
        if (t + 1 < CT) {
            size_t rn = row + 1;
            dt_n = dt[rn * DI + d];
            x_n  = xconv[rn * DI + d];
            B_n  = xdbl[rn * 96 + 64 + n];
        }
        float dA = __expf(Aval * dt_c);
        P *= dA;
        S = dA * S + (dt_c * x_c) * B_c;
        dt_c = dt_n; x_c = x_n; B_c = B_n;
    }

    size_t o = (((size_t)(b * NCHUNK + c)) * DI + d) * 16 + n;
    Pc[o] = P; Sc[o] = S;
}

// Pass C (with fused inter-chunk prefix): h_start = scan of Pc/Sc over c'<c,
// then redo local scan, fuse skip + gate, write gated over xconv.
__global__ __launch_bounds__(256) void scan_passC2(
    const float* __restrict__ dt,     // [4096][2048]
    const float* __restrict__ xdbl,   // [4096][96]
    const float* __restrict__ xz,     // [4096][4096] (z at cols 2048..4095)
    float* __restrict__ xconv,        // in: x_conv, out: gated
    const float* __restrict__ A_log,  // [2048][16]
    const float* __restrict__ Dp,     // [2048]
    const float* __restrict__ Pc,     // [2][16][2048][16]
    const float* __restrict__ Sc)     // [2][16][2048][16]
{
    const int DI = 2048, L = 2048;
    const int n   = threadIdx.x & 15;
    const int chi = threadIdx.x >> 4;
    const int bid = blockIdx.x;
    const int dg  = bid & 127;
    const int c   = (bid >> 7) & 15;
    const int b   = bid >> 11;
    const int d   = dg * 16 + chi;

    const float Aval = -expf(A_log[d * 16 + n]);
    const float Dval = Dp[d];
    const size_t rowBase = (size_t)b * L + (size_t)c * CT;

    // inter-chunk prefix: state at the start of chunk c (<=15 iters)
    float h = 0.f;
    for (int cp = 0; cp < c; ++cp) {
        size_t o = (((size_t)(b * NCHUNK + cp)) * DI + d) * 16 + n;
        h = Pc[o] * h + Sc[o];
    }

    float dt_c = dt[rowBase * DI + d];
    float x_c  = xconv[rowBase * DI + d];
    float B_c  = xdbl[rowBase * 96 + 64 + n];
    float C_c  = xdbl[rowBase * 96 + 80 + n];

    for (int t = 0; t < CT; ++t) {
        size_t row = rowBase + t;
        float dt_n = 0.f, x_n = 0.f, B_n = 0.f, C_n = 0.f;
        if (t + 1 < CT) {
            size_t rn = row + 1;
            dt_n = dt[rn * DI + d];
            x_n  = xconv[rn * DI + d];
            B_n  = xdbl[rn * 96 + 64 + n];
            C_n  = xdbl[rn * 96 + 80 + n];
        }

        float dA = __expf(Aval * dt_c);
        h = dA * h + (dt_c * x_c) * B_c;
        float p = h * C_c;
        p += __shfl_xor(p, 1, 16);
        p += __shfl_xor(p, 2, 16);
        p += __shfl_xor(p, 4, 16);
        p += __shfl_xor(p, 8, 16);

        if (n == 0) {
            float y = p + x_c * Dval;
            float zv = xz[row * 4096 + 2048 + d];
            float sz = zv / (1.f + __expf(-zv));
            xconv[row * DI + d] = y * sz;
        }

        dt_c = dt_n; x_c = x_n; B_c = B_n; C_c = C_n;
    }
}

// ---------------- monolithic scan (round-4 proven; ws-size fallback) ---------
__global__ __launch_bounds__(256) void scan_kernel(
    const float* __restrict__ dt, const float* __restrict__ xdbl,
    const float* __restrict__ xz, float* __restrict__ xconv,
    const float* __restrict__ A_log, const float* __restrict__ Dp)
{
    const int L = 2048, DI = 2048;
    const int n = threadIdx.x & 15;
    const int chi = threadIdx.x >> 4;
    const int b = blockIdx.x / 128;
    const int d = (blockIdx.x % 128) * 16 + chi;

    const float Aval = -expf(A_log[d * 16 + n]);
    const float Dval = Dp[d];
    float h = 0.f;
    const size_t rowBase = (size_t)b * L;

    float dt_c = dt[rowBase * DI + d];
    float x_c  = xconv[rowBase * DI + d];
    float B_c  = xdbl[rowBase * 96 + 64 + n];
    float C_c  = xdbl[rowBase * 96 + 80 + n];

    for (int t = 0; t < L; ++t) {
        size_t row = rowBase + t;
        float dt_n = 0.f, x_n = 0.f, B_n = 0.f, C_n = 0.f;
        if (t + 1 < L) {
            size_t rn = row + 1;
            dt_n = dt[rn * DI + d];
            x_n  = xconv[rn * DI + d];
            B_n  = xdbl[rn * 96 + 64 + n];
            C_n  = xdbl[rn * 96 + 80 + n];
        }
        float dA = __expf(Aval * dt_c);
        h = dA * h + (dt_c * x_c) * B_c;
        float p = h * C_c;
        p += __shfl_xor(p, 1, 16);
        p += __shfl_xor(p, 2, 16);
        p += __shfl_xor(p, 4, 16);
        p += __shfl_xor(p, 8, 16);
        if (n == 0) {
            float y = p + x_c * Dval;
            float zv = xz[row * 4096 + 2048 + d];
            float sz = zv / (1.f + __expf(-zv));
            xconv[row * DI + d] = y * sz;
        }
        dt_c = dt_n; x_c = x_n; B_c = B_n; C_c = C_n;
    }
}

extern "C" void kernel_launch(void* const* d_in, const int* in_sizes, int n_in,
                              void* d_out, int out_size, void* d_ws, size_t ws_size,
                              hipStream_t stream)
{
    const float* x     = (const float*)d_in[0];
    const float* W_in  = (const float*)d_in[1];
    const float* b_in  = (const float*)d_in[2];
    const float* W_x   = (const float*)d_in[3];
    const float* b_x   = (const float*)d_in[4];
    const float* W_dt  = (const float*)d_in[5];
    const float* b_dt  = (const float*)d_in[6];
    const float* A_log = (const float*)d_in[7];
    const float* Dp    = (const float*)d_in[8];
    const float* W_out = (const float*)d_in[9];
    const float* b_out = (const float*)d_in[10];
    float* out = (float*)d_out;

    float* ws    = (float*)d_ws;
    float* xz    = ws;                       // 16,777,216 f32
    float* xconv = xz + 16777216;            //  8,388,608 f32
    float* xdbl  = xconv + 8388608;          //    393,216 f32
    float* dtbuf = xdbl + 393216;            //  8,388,608 f32
    float* Pc    = dtbuf + 8388608;          //  1,048,576 f32 (full path only)
    float* Sc    = Pc + 1048576;             //  1,048,576 f32 (full path only)

    const size_t base_f32 = 16777216 + 8388608 + 393216 + 8388608;   // floats
    const size_t wshorts  = 4096 * 1024 + 96 * 2048 + 2048 * 64 + 1024 * 2048;
    const size_t needed_full = (base_f32 + 2 * 1048576) * 4 + wshorts * 2; // 157,417,472
    const size_t needed_fall = base_f32 * 4 + wshorts * 2;                 // 149,028,864

    const bool fullpath = ws_size >= needed_full;       // constant per problem
    if (!fullpath && ws_size < needed_fall) return;     // tripwire: clean fail

    // weights: no aliasing with anything; compact placement on fallback path
    unsigned short* wbuf = fullpath ? (unsigned short*)(Sc + 1048576)
                                    : (unsigned short*)Pc;
    unsigned short* WinT  = wbuf;                  // [4096][1024] bf16
    unsigned short* WxT   = WinT  + 4096 * 1024;   // [96][2048]
    unsigned short* WdtT  = WxT   + 96 * 2048;     // [2048][64]
    unsigned short* WoutT = WdtT  + 2048 * 64;     // [1024][2048]

    dim3 tblk(32, 8);
    transpose_bf16<<<dim3(128, 32), tblk, 0, stream>>>(W_in, WinT, 1024, 4096);
    transpose_bf16<<<dim3(3, 64),   tblk, 0, stream>>>(W_x,  WxT,  2048, 96);
    transpose_bf16<<<dim3(64, 2),   tblk, 0, stream>>>(W_dt, WdtT, 64, 2048);
    transpose_bf16<<<dim3(32, 64),  tblk, 0, stream>>>(W_out,WoutT,2048, 1024);

    dim3 blk(256);

    // 1) xz = x @ W_in + b_in   (M=4096, N=4096, K=1024)
    gemm_mfma<0><<<dim3(32, 32), blk, 0, stream>>>(
        x, 1024, WinT, 1024, b_in, xz, 4096, 4096, 4096, 1024);

    // 2) x_conv = silu(causal mean3(x_inner))
    conv_silu<<<(4096 * 2048 + 255) / 256, blk, 0, stream>>>(xz, xconv);

    // 3) x_dbl = x_conv @ W_x + b_x   (M=4096, N=96, K=2048)
    gemm_mfma<0><<<dim3(1, 32), blk, 0, stream>>>(
        xconv, 2048, WxT, 2048, b_x, xdbl, 96, 4096, 96, 2048);

    // 4) dt = softplus(x_dbl[:, :64] @ W_dt + b_dt)   (M=4096, N=2048, K=64)
    gemm_mfma<1><<<dim3(16, 32), blk, 0, stream>>>(
        xdbl, 96, WdtT, 64, b_dt, dtbuf, 2048, 4096, 2048, 64);

    // 5) selective scan (+ skip, + gate) -> gated stored over xconv
    if (fullpath) {
        scan_passA<<<4096, blk, 0, stream>>>(dtbuf, xdbl, xconv, A_log, Pc, Sc);
        scan_passC2<<<4096, blk, 0, stream>>>(dtbuf, xdbl, xz, xconv, A_log, Dp, Pc, Sc);
    } else {
        scan_kernel<<<256, blk, 0, stream>>>(dtbuf, xdbl, xz, xconv, A_log, Dp);
    }

    // 6) out = gated @ W_out + b_out   (M=4096, N=1024, K=2048)
    gemm_mfma<0><<<dim3(8, 32), blk, 0, stream>>>(
        xconv, 2048, WoutT, 2048, b_out, out, 1024, 4096, 1024, 2048);
}

// Round 7
// 665.444 us; speedup vs baseline: 2.5816x; 1.1825x over previous
//
#include <hip/hip_runtime.h>
#include <hip/hip_bf16.h>

typedef __attribute__((ext_vector_type(8))) short short8;
typedef __attribute__((ext_vector_type(4))) float f32x4;
typedef __attribute__((ext_vector_type(4))) float float4v;

#define NCHUNK 16
#define CT 128   // chunk length (NCHUNK*CT == L == 2048)

static __device__ __forceinline__ unsigned short f2bf(float f) {
    union { float f; unsigned u; } v; v.f = f;
    unsigned r = v.u + 0x7fff + ((v.u >> 16) & 1);   // round-to-nearest-even
    return (unsigned short)(r >> 16);
}

// ---------------- transpose + f32->bf16 convert: out[c][r] = bf16(in[r][c]) --
__global__ __launch_bounds__(256) void transpose_bf16(
    const float* __restrict__ in, unsigned short* __restrict__ out, int R, int Cc)
{
    __shared__ float tile[32][33];
    int c0 = blockIdx.x * 32, r0 = blockIdx.y * 32;
    int tx = threadIdx.x, ty = threadIdx.y;      // 32 x 8
#pragma unroll
    for (int i = 0; i < 32; i += 8) {
        int r = r0 + ty + i, c = c0 + tx;
        tile[ty + i][tx] = (r < R && c < Cc) ? in[(size_t)r * Cc + c] : 0.f;
    }
    __syncthreads();
#pragma unroll
    for (int i = 0; i < 32; i += 8) {
        int c = c0 + ty + i, r = r0 + tx;        // out[c][r]
        if (c < Cc && r < R) out[(size_t)c * R + r] = f2bf(tile[tx][ty + i]);
    }
}

// ---------------- MFMA GEMM: C = A @ Bt^T + bias, optional softplus ----------
// A: f32 [M][lda] (converted to bf16 during staging). Bt: bf16 [N][ldb].
// Tile 128x128, BK=32. 4 waves, each owns a 64x64 quadrant (4x4 MFMA frags).
template <int ACT>
__global__ __launch_bounds__(256) void gemm_mfma(
    const float* __restrict__ A, int lda,
    const unsigned short* __restrict__ Bt, int ldb,
    const float* __restrict__ bias,
    float* __restrict__ C, int ldc,
    int M, int N, int K)
{
    __shared__ unsigned short As[128 * 32];
    __shared__ unsigned short Bs[128 * 32];

    const int tid  = threadIdx.x;
    const int lane = tid & 63;
    const int wave = tid >> 6;
    const int g    = lane >> 4;        // k-group 0..3
    const int r16  = lane & 15;
    const int wr   = (wave >> 1) * 64; // wave row offset in tile
    const int wc   = (wave & 1) * 64;  // wave col offset in tile
    const int rowBase = blockIdx.y * 128;
    const int colBase = blockIdx.x * 128;

    f32x4 acc[4][4] = {};

    for (int k0 = 0; k0 < K; k0 += 32) {
        // ---- stage A (f32 -> bf16): 128 rows x 32 k = 512 chunks of 8
#pragma unroll
        for (int c = 0; c < 2; ++c) {
            int chunk = c * 256 + tid;
            int r = chunk >> 2;            // tile row
            int slot = chunk & 3;          // 8-element k slot
            int gr = rowBase + r;
            short8 t = {};
            if (gr < M) {
                const float* src = A + (size_t)gr * lda + k0 + slot * 8;
                float4v v0 = *reinterpret_cast<const float4v*>(src);
                float4v v1 = *reinterpret_cast<const float4v*>(src + 4);
                t[0] = (short)f2bf(v0[0]); t[1] = (short)f2bf(v0[1]);
                t[2] = (short)f2bf(v0[2]); t[3] = (short)f2bf(v0[3]);
                t[4] = (short)f2bf(v1[0]); t[5] = (short)f2bf(v1[1]);
                t[6] = (short)f2bf(v1[2]); t[7] = (short)f2bf(v1[3]);
            }
            int sslot = slot ^ (r & 3);    // XOR swizzle (both sides)
            *reinterpret_cast<short8*>(&As[r * 32 + sslot * 8]) = t;
        }
        // ---- stage Bt (already bf16): 128 rows(=out cols) x 32 k
#pragma unroll
        for (int c = 0; c < 2; ++c) {
            int chunk = c * 256 + tid;
            int r = chunk >> 2;
            int slot = chunk & 3;
            int gn = colBase + r;
            short8 t = {};
            if (gn < N)
                t = *reinterpret_cast<const short8*>(Bt + (size_t)gn * ldb + k0 + slot * 8);
            int sslot = slot ^ (r & 3);
            *reinterpret_cast<short8*>(&Bs[r * 32 + sslot * 8]) = t;
        }
        __syncthreads();

        // ---- fragments: lane reads 8 consecutive k (same mapping for A and B)
        short8 af[4], bfr[4];
#pragma unroll
        for (int m = 0; m < 4; ++m) {
            int r = wr + m * 16 + r16;
            int sslot = g ^ (r & 3);
            af[m] = *reinterpret_cast<const short8*>(&As[r * 32 + sslot * 8]);
        }
#pragma unroll
        for (int n = 0; n < 4; ++n) {
            int r = wc + n * 16 + r16;
            int sslot = g ^ (r & 3);
            bfr[n] = *reinterpret_cast<const short8*>(&Bs[r * 32 + sslot * 8]);
        }
#pragma unroll
        for (int m = 0; m < 4; ++m)
#pragma unroll
            for (int n = 0; n < 4; ++n)
                acc[m][n] = __builtin_amdgcn_mfma_f32_16x16x32_bf16(
                    af[m], bfr[n], acc[m][n], 0, 0, 0);
        __syncthreads();
    }

    // ---- epilogue: D row = g*4 + v (A-side), col = r16 (B-side)  [m89/m91]
#pragma unroll
    for (int m = 0; m < 4; ++m) {
#pragma unroll
        for (int v = 0; v < 4; ++v) {
            int gr = rowBase + wr + m * 16 + g * 4 + v;
            if (gr >= M) continue;
#pragma unroll
            for (int n = 0; n < 4; ++n) {
                int gc = colBase + wc + n * 16 + r16;
                if (gc >= N) continue;
                float val = acc[m][n][v] + bias[gc];
                if (ACT == 1) val = (val > 20.f) ? val : log1pf(expf(val));
                C[(size_t)gr * ldc + gc] = val;
            }
        }
    }
}

// ---------------- depthwise causal conv (mean of 3) + SiLU -------------------
__global__ __launch_bounds__(256) void conv_silu(
    const float* __restrict__ xz, float* __restrict__ xconv)
{
    int idx = blockIdx.x * blockDim.x + threadIdx.x;
    if (idx >= 4096 * 2048) return;
    int d = idx & 2047;
    int row = idx >> 11;        // row = b*2048 + l
    int l = row & 2047;

    float s = xz[(size_t)row * 4096 + d];
    if (l >= 1) s += xz[(size_t)(row - 1) * 4096 + d];
    if (l >= 2) s += xz[(size_t)(row - 2) * 4096 + d];
    s *= (1.f / 3.f);
    float sv = s / (1.f + __expf(-s));
    xconv[idx] = sv;
}

// ---------------- chunked selective scan, 4-states-per-lane ------------------
// Lane layout within wave: chi = lane&15 (channel), ng = lane>>4 (state group).
// Thread handles states n = ng*4 .. ng*4+3 of channel d in f32x4 registers.
// Block = (b, chunk, 64-channel group); B/C staged in LDS (broadcast reads).

// Pass A: per chunk with h_in = 0: P = prod(dA) (x4), S = local final state.
__global__ __launch_bounds__(256) void scan_passA(
    const float* __restrict__ dt,     // [4096][2048]
    const float* __restrict__ xdbl,   // [4096][96]
    const float* __restrict__ xconv,  // [4096][2048]
    const float* __restrict__ A_log,  // [2048][16]
    float* __restrict__ Pc,           // [2][16][2048][16]
    float* __restrict__ Sc)           // [2][16][2048][16]
{
    __shared__ float sBC[CT][32];
    const int tid  = threadIdx.x;
    const int bid  = blockIdx.x;         // 1024 = b(2) x c(16) x dg(32)
    const int dg   = bid & 31;
    const int c    = (bid >> 5) & 15;
    const int b    = bid >> 9;
    const int lane = tid & 63;
    const int wave = tid >> 6;
    const int chi  = lane & 15;
    const int ng   = lane >> 4;          // 0..3
    const int d    = dg * 64 + wave * 16 + chi;
    const size_t rowBase = (size_t)b * 2048 + (size_t)c * CT;

    // stage B/C: xdbl[row][64..95] -> sBC[t][0..31]  (float4, lane-linear)
    for (int i = tid; i < CT * 8; i += 256) {
        int tt = i >> 3, q = i & 7;
        *reinterpret_cast<float4v*>(&sBC[tt][q * 4]) =
            *reinterpret_cast<const float4v*>(&xdbl[(rowBase + tt) * 96 + 64 + q * 4]);
    }
    __syncthreads();

    float4v Aval, h = {}, P = {1.f, 1.f, 1.f, 1.f};
#pragma unroll
    for (int j = 0; j < 4; ++j) Aval[j] = -expf(A_log[d * 16 + ng * 4 + j]);

    const float* pdt = dt + rowBase * 2048 + d;
    const float* px  = xconv + rowBase * 2048 + d;
    float dt_c = *pdt, x_c = *px;
    for (int t = 0; t < CT; ++t) {
        float dt_n = 0.f, x_n = 0.f;
        if (t + 1 < CT) { dt_n = pdt[2048]; x_n = px[2048]; }
        pdt += 2048; px += 2048;

        float4v Bv = *reinterpret_cast<const float4v*>(&sBC[t][ng * 4]);
        float u = dt_c * x_c;
#pragma unroll
        for (int j = 0; j < 4; ++j) {
            float dA = __expf(Aval[j] * dt_c);
            P[j] *= dA;
            h[j] = dA * h[j] + u * Bv[j];
        }
        dt_c = dt_n; x_c = x_n;
    }
    size_t o = (((size_t)(b * NCHUNK + c)) * 2048 + d) * 16 + ng * 4;
    *reinterpret_cast<float4v*>(&Pc[o]) = P;
    *reinterpret_cast<float4v*>(&Sc[o]) = h;
}

// Pass C: inter-chunk prefix from Pc/Sc, local rescan, fused skip+gate.
__global__ __launch_bounds__(256) void scan_passC2(
    const float* __restrict__ dt,     // [4096][2048]
    const float* __restrict__ xdbl,   // [4096][96]
    const float* __restrict__ xz,     // [4096][4096] (z at cols 2048..4095)
    float* __restrict__ xconv,        // in: x_conv, out: gated
    const float* __restrict__ A_log,  // [2048][16]
    const float* __restrict__ Dp,     // [2048]
    const float* __restrict__ Pc,     // [2][16][2048][16]
    const float* __restrict__ Sc)     // [2][16][2048][16]
{
    __shared__ float sBC[CT][32];
    const int tid  = threadIdx.x;
    const int bid  = blockIdx.x;
    const int dg   = bid & 31;
    const int c    = (bid >> 5) & 15;
    const int b    = bid >> 9;
    const int lane = tid & 63;
    const int wave = tid >> 6;
    const int chi  = lane & 15;
    const int ng   = lane >> 4;
    const int d    = dg * 64 + wave * 16 + chi;
    const size_t rowBase = (size_t)b * 2048 + (size_t)c * CT;

    for (int i = tid; i < CT * 8; i += 256) {
        int tt = i >> 3, q = i & 7;
        *reinterpret_cast<float4v*>(&sBC[tt][q * 4]) =
            *reinterpret_cast<const float4v*>(&xdbl[(rowBase + tt) * 96 + 64 + q * 4]);
    }
    __syncthreads();

    float4v Aval, h = {};
#pragma unroll
    for (int j = 0; j < 4; ++j) Aval[j] = -expf(A_log[d * 16 + ng * 4 + j]);
    const float Dval = Dp[d];

    // inter-chunk prefix: state at start of chunk c (<=15 iters, float4 loads)
    for (int cp = 0; cp < c; ++cp) {
        size_t o = (((size_t)(b * NCHUNK + cp)) * 2048 + d) * 16 + ng * 4;
        float4v Pv = *reinterpret_cast<const float4v*>(&Pc[o]);
        float4v Sv = *reinterpret_cast<const float4v*>(&Sc[o]);
#pragma unroll
        for (int j = 0; j < 4; ++j) h[j] = Pv[j] * h[j] + Sv[j];
    }

    const float* pdt = dt + rowBase * 2048 + d;
    const float* px  = xconv + rowBase * 2048 + d;
    const float* pz  = xz + rowBase * 4096 + 2048 + d;
    float* pw        = xconv + rowBase * 2048 + d;
    float dt_c = *pdt, x_c = *px;

    for (int t = 0; t < CT; ++t) {
        float dt_n = 0.f, x_n = 0.f;
        if (t + 1 < CT) { dt_n = pdt[2048]; x_n = px[2048]; }
        pdt += 2048; px += 2048;

        float4v Bv = *reinterpret_cast<const float4v*>(&sBC[t][ng * 4]);
        float4v Cv = *reinterpret_cast<const float4v*>(&sBC[t][16 + ng * 4]);
        float u = dt_c * x_c;
        float p = 0.f;
#pragma unroll
        for (int j = 0; j < 4; ++j) {
            float dA = __expf(Aval[j] * dt_c);
            h[j] = dA * h[j] + u * Bv[j];
            p += h[j] * Cv[j];
        }
        p += __shfl_xor(p, 16);
        p += __shfl_xor(p, 32);

        if (ng == 0) {
            float y = p + x_c * Dval;
            float zv = *pz;
            float sz = zv / (1.f + __expf(-zv));
            *pw = y * sz;
        }
        pz += 4096; pw += 2048;
        dt_c = dt_n; x_c = x_n;
    }
}

// ---------------- monolithic scan (round-4 proven; ws-size fallback) ---------
__global__ __launch_bounds__(256) void scan_kernel(
    const float* __restrict__ dt, const float* __restrict__ xdbl,
    const float* __restrict__ xz, float* __restrict__ xconv,
    const float* __restrict__ A_log, const float* __restrict__ Dp)
{
    const int L = 2048, DI = 2048;
    const int n = threadIdx.x & 15;
    const int chi = threadIdx.x >> 4;
    const int b = blockIdx.x / 128;
    const int d = (blockIdx.x % 128) * 16 + chi;

    const float Aval = -expf(A_log[d * 16 + n]);
    const float Dval = Dp[d];
    float h = 0.f;
    const size_t rowBase = (size_t)b * L;

    float dt_c = dt[rowBase * DI + d];
    float x_c  = xconv[rowBase * DI + d];
    float B_c  = xdbl[rowBase * 96 + 64 + n];
    float C_c  = xdbl[rowBase * 96 + 80 + n];

    for (int t = 0; t < L; ++t) {
        size_t row = rowBase + t;
        float dt_n = 0.f, x_n = 0.f, B_n = 0.f, C_n = 0.f;
        if (t + 1 < L) {
            size_t rn = row + 1;
            dt_n = dt[rn * DI + d];
            x_n  = xconv[rn * DI + d];
            B_n  = xdbl[rn * 96 + 64 + n];
            C_n  = xdbl[rn * 96 + 80 + n];
        }
        float dA = __expf(Aval * dt_c);
        h = dA * h + (dt_c * x_c) * B_c;
        float p = h * C_c;
        p += __shfl_xor(p, 1, 16);
        p += __shfl_xor(p, 2, 16);
        p += __shfl_xor(p, 4, 16);
        p += __shfl_xor(p, 8, 16);
        if (n == 0) {
            float y = p + x_c * Dval;
            float zv = xz[row * 4096 + 2048 + d];
            float sz = zv / (1.f + __expf(-zv));
            xconv[row * DI + d] = y * sz;
        }
        dt_c = dt_n; x_c = x_n; B_c = B_n; C_c = C_n;
    }
}

extern "C" void kernel_launch(void* const* d_in, const int* in_sizes, int n_in,
                              void* d_out, int out_size, void* d_ws, size_t ws_size,
                              hipStream_t stream)
{
    const float* x     = (const float*)d_in[0];
    const float* W_in  = (const float*)d_in[1];
    const float* b_in  = (const float*)d_in[2];
    const float* W_x   = (const float*)d_in[3];
    const float* b_x   = (const float*)d_in[4];
    const float* W_dt  = (const float*)d_in[5];
    const float* b_dt  = (const float*)d_in[6];
    const float* A_log = (const float*)d_in[7];
    const float* Dp    = (const float*)d_in[8];
    const float* W_out = (const float*)d_in[9];
    const float* b_out = (const float*)d_in[10];
    float* out = (float*)d_out;

    float* ws    = (float*)d_ws;
    float* xz    = ws;                       // 16,777,216 f32
    float* xconv = xz + 16777216;            //  8,388,608 f32
    float* xdbl  = xconv + 8388608;          //    393,216 f32
    float* dtbuf = xdbl + 393216;            //  8,388,608 f32
    float* Pc    = dtbuf + 8388608;          //  1,048,576 f32 (full path only)
    float* Sc    = Pc + 1048576;             //  1,048,576 f32 (full path only)

    const size_t base_f32 = 16777216 + 8388608 + 393216 + 8388608;   // floats
    const size_t wshorts  = 4096 * 1024 + 96 * 2048 + 2048 * 64 + 1024 * 2048;
    const size_t needed_full = (base_f32 + 2 * 1048576) * 4 + wshorts * 2; // 157,417,472
    const size_t needed_fall = base_f32 * 4 + wshorts * 2;                 // 149,028,864

    const bool fullpath = ws_size >= needed_full;       // constant per problem
    if (!fullpath && ws_size < needed_fall) return;     // tripwire: clean fail

    unsigned short* wbuf = fullpath ? (unsigned short*)(Sc + 1048576)
                                    : (unsigned short*)Pc;
    unsigned short* WinT  = wbuf;                  // [4096][1024] bf16
    unsigned short* WxT   = WinT  + 4096 * 1024;   // [96][2048]
    unsigned short* WdtT  = WxT   + 96 * 2048;     // [2048][64]
    unsigned short* WoutT = WdtT  + 2048 * 64;     // [1024][2048]

    dim3 tblk(32, 8);
    transpose_bf16<<<dim3(128, 32), tblk, 0, stream>>>(W_in, WinT, 1024, 4096);
    transpose_bf16<<<dim3(3, 64),   tblk, 0, stream>>>(W_x,  WxT,  2048, 96);
    transpose_bf16<<<dim3(64, 2),   tblk, 0, stream>>>(W_dt, WdtT, 64, 2048);
    transpose_bf16<<<dim3(32, 64),  tblk, 0, stream>>>(W_out,WoutT,2048, 1024);

    dim3 blk(256);

    // 1) xz = x @ W_in + b_in   (M=4096, N=4096, K=1024)
    gemm_mfma<0><<<dim3(32, 32), blk, 0, stream>>>(
        x, 1024, WinT, 1024, b_in, xz, 4096, 4096, 4096, 1024);

    // 2) x_conv = silu(causal mean3(x_inner))
    conv_silu<<<(4096 * 2048 + 255) / 256, blk, 0, stream>>>(xz, xconv);

    // 3) x_dbl = x_conv @ W_x + b_x   (M=4096, N=96, K=2048)
    gemm_mfma<0><<<dim3(1, 32), blk, 0, stream>>>(
        xconv, 2048, WxT, 2048, b_x, xdbl, 96, 4096, 96, 2048);

    // 4) dt = softplus(x_dbl[:, :64] @ W_dt + b_dt)   (M=4096, N=2048, K=64)
    gemm_mfma<1><<<dim3(16, 32), blk, 0, stream>>>(
        xdbl, 96, WdtT, 64, b_dt, dtbuf, 2048, 4096, 2048, 64);

    // 5) selective scan (+ skip, + gate) -> gated stored over xconv
    if (fullpath) {
        scan_passA<<<1024, blk, 0, stream>>>(dtbuf, xdbl, xconv, A_log, Pc, Sc);
        scan_passC2<<<1024, blk, 0, stream>>>(dtbuf, xdbl, xz, xconv, A_log, Dp, Pc, Sc);
    } else {
        scan_kernel<<<256, blk, 0, stream>>>(dtbuf, xdbl, xz, xconv, A_log, Dp);
    }

    // 6) out = gated @ W_out + b_out   (M=4096, N=1024, K=2048)
    gemm_mfma<0><<<dim3(8, 32), blk, 0, stream>>>(
        xconv, 2048, WoutT, 2048, b_out, out, 1024, 4096, 1024, 2048);
}

// Round 8
// 493.630 us; speedup vs baseline: 3.4802x; 1.3481x over previous
//
#include <hip/hip_runtime.h>
#include <hip/hip_bf16.h>

typedef __attribute__((ext_vector_type(8))) short short8;
typedef __attribute__((ext_vector_type(4))) float f32x4;
typedef __attribute__((ext_vector_type(4))) float float4v;

#define NCHUNK 16
#define CT 128   // chunk length (NCHUNK*CT == L == 2048)

static __device__ __forceinline__ unsigned short f2bf(float f) {
    union { float f; unsigned u; } v; v.f = f;
    unsigned r = v.u + 0x7fff + ((v.u >> 16) & 1);   // round-to-nearest-even
    return (unsigned short)(r >> 16);
}

static __device__ __forceinline__ void gld16(const unsigned short* g, unsigned short* l) {
    __builtin_amdgcn_global_load_lds(
        (const __attribute__((address_space(1))) void*)g,
        (__attribute__((address_space(3))) void*)l, 16, 0, 0);
}

// ---------------- f32 -> bf16 elementwise cast (8 elems/thread) --------------
__global__ __launch_bounds__(256) void cast_bf16(
    const float* __restrict__ in, unsigned short* __restrict__ out, int n8)
{
    int i = blockIdx.x * 256 + threadIdx.x;
    if (i >= n8) return;
    const float4v v0 = *reinterpret_cast<const float4v*>(in + (size_t)i * 8);
    const float4v v1 = *reinterpret_cast<const float4v*>(in + (size_t)i * 8 + 4);
    short8 t;
    t[0] = (short)f2bf(v0[0]); t[1] = (short)f2bf(v0[1]);
    t[2] = (short)f2bf(v0[2]); t[3] = (short)f2bf(v0[3]);
    t[4] = (short)f2bf(v1[0]); t[5] = (short)f2bf(v1[1]);
    t[6] = (short)f2bf(v1[2]); t[7] = (short)f2bf(v1[3]);
    *reinterpret_cast<short8*>(out + (size_t)i * 8) = t;
}

// ---------------- transpose + f32->bf16 convert: out[c][r] = bf16(in[r][c]) --
__global__ __launch_bounds__(256) void transpose_bf16(
    const float* __restrict__ in, unsigned short* __restrict__ out, int R, int Cc)
{
    __shared__ float tile[32][33];
    int c0 = blockIdx.x * 32, r0 = blockIdx.y * 32;
    int tx = threadIdx.x, ty = threadIdx.y;      // 32 x 8
#pragma unroll
    for (int i = 0; i < 32; i += 8) {
        int r = r0 + ty + i, c = c0 + tx;
        tile[ty + i][tx] = (r < R && c < Cc) ? in[(size_t)r * Cc + c] : 0.f;
    }
    __syncthreads();
#pragma unroll
    for (int i = 0; i < 32; i += 8) {
        int c = c0 + ty + i, r = r0 + tx;        // out[c][r]
        if (c < Cc && r < R) out[(size_t)c * R + r] = f2bf(tile[tx][ty + i]);
    }
}

// ---------------- bf16 MFMA GEMM (m97 structure): C = A @ Bt^T + bias --------
// A: bf16 [M][lda], Bt: bf16 [N][ldb]. Tile 128x128, BK=32, 4 waves.
// global_load_lds width-16 staging, linear LDS, 8 ds_read_b128 + 16 MFMA/wave.
// M must be a multiple of 128; N may be < tile (guarded in epilogue; B OOB
// rows read adjacent ws memory - finite bf16, never stored).
// AUX: also write bf16(val) to Cbf[gr*ldcbf+gc] for gc < ncbf.
template <int ACT, bool AUX>
__global__ __launch_bounds__(256) void gemm_bf(
    const unsigned short* __restrict__ A, int lda,
    const unsigned short* __restrict__ Bt, int ldb,
    const float* __restrict__ bias,
    float* __restrict__ C, int ldc,
    unsigned short* __restrict__ Cbf, int ldcbf, int ncbf,
    int N, int K)
{
    __shared__ __align__(16) unsigned short As[128 * 32];
    __shared__ __align__(16) unsigned short Bs[128 * 32];

    const int tid  = threadIdx.x;
    const int lane = tid & 63;
    const int wave = tid >> 6;
    const int g    = lane >> 4;        // k-group 0..3
    const int r16  = lane & 15;
    const int wr   = (wave >> 1) * 64;
    const int wc   = (wave & 1) * 64;
    const int rowBase = blockIdx.y * 128;
    const int colBase = blockIdx.x * 128;

    // two gload invocations per operand: elem e = (i*256+tid)*8, r=e>>5, c=e&31
    const int e0 = tid * 8;
    const int e1 = (256 + tid) * 8;
    const int r0 = e0 >> 5, c0 = e0 & 31;
    const int r1 = e1 >> 5, c1 = e1 & 31;
    const unsigned short* a0 = A + (size_t)(rowBase + r0) * lda + c0;
    const unsigned short* a1 = A + (size_t)(rowBase + r1) * lda + c1;
    const unsigned short* b0 = Bt + (size_t)(colBase + r0) * ldb + c0;
    const unsigned short* b1 = Bt + (size_t)(colBase + r1) * ldb + c1;

    f32x4 acc[4][4] = {};

    for (int k0 = 0; k0 < K; k0 += 32) {
        gld16(a0 + k0, As + e0);
        gld16(a1 + k0, As + e1);
        gld16(b0 + k0, Bs + e0);
        gld16(b1 + k0, Bs + e1);
        __syncthreads();   // drains vmcnt before barrier (compiler-inserted)

        short8 af[4], bfr[4];
#pragma unroll
        for (int m = 0; m < 4; ++m)
            af[m] = *reinterpret_cast<const short8*>(&As[(wr + m * 16 + r16) * 32 + g * 8]);
#pragma unroll
        for (int n = 0; n < 4; ++n)
            bfr[n] = *reinterpret_cast<const short8*>(&Bs[(wc + n * 16 + r16) * 32 + g * 8]);
#pragma unroll
        for (int m = 0; m < 4; ++m)
#pragma unroll
            for (int n = 0; n < 4; ++n)
                acc[m][n] = __builtin_amdgcn_mfma_f32_16x16x32_bf16(
                    af[m], bfr[n], acc[m][n], 0, 0, 0);
        __syncthreads();
    }

    // epilogue: D row = g*4 + v (A-side), col = r16 (B-side)  [m89/m91]
#pragma unroll
    for (int m = 0; m < 4; ++m) {
#pragma unroll
        for (int v = 0; v < 4; ++v) {
            int gr = rowBase + wr + m * 16 + g * 4 + v;
#pragma unroll
            for (int n = 0; n < 4; ++n) {
                int gc = colBase + wc + n * 16 + r16;
                if (gc >= N) continue;
                float val = acc[m][n][v] + bias[gc];
                if (ACT == 1) val = (val > 20.f) ? val : log1pf(expf(val));
                C[(size_t)gr * ldc + gc] = val;
                if (AUX && gc < ncbf)
                    Cbf[(size_t)gr * ldcbf + gc] = f2bf(val);
            }
        }
    }
}

// ---------------- f32-A MFMA GEMM (round-7 proven; tier-2 fallback) ----------
template <int ACT>
__global__ __launch_bounds__(256) void gemm_mfma(
    const float* __restrict__ A, int lda,
    const unsigned short* __restrict__ Bt, int ldb,
    const float* __restrict__ bias,
    float* __restrict__ C, int ldc,
    int M, int N, int K)
{
    __shared__ unsigned short As[128 * 32];
    __shared__ unsigned short Bs[128 * 32];

    const int tid  = threadIdx.x;
    const int lane = tid & 63;
    const int wave = tid >> 6;
    const int g    = lane >> 4;
    const int r16  = lane & 15;
    const int wr   = (wave >> 1) * 64;
    const int wc   = (wave & 1) * 64;
    const int rowBase = blockIdx.y * 128;
    const int colBase = blockIdx.x * 128;

    f32x4 acc[4][4] = {};

    for (int k0 = 0; k0 < K; k0 += 32) {
#pragma unroll
        for (int c = 0; c < 2; ++c) {
            int chunk = c * 256 + tid;
            int r = chunk >> 2, slot = chunk & 3;
            int gr = rowBase + r;
            short8 t = {};
            if (gr < M) {
                const float* src = A + (size_t)gr * lda + k0 + slot * 8;
                float4v v0 = *reinterpret_cast<const float4v*>(src);
                float4v v1 = *reinterpret_cast<const float4v*>(src + 4);
                t[0] = (short)f2bf(v0[0]); t[1] = (short)f2bf(v0[1]);
                t[2] = (short)f2bf(v0[2]); t[3] = (short)f2bf(v0[3]);
                t[4] = (short)f2bf(v1[0]); t[5] = (short)f2bf(v1[1]);
                t[6] = (short)f2bf(v1[2]); t[7] = (short)f2bf(v1[3]);
            }
            int sslot = slot ^ (r & 3);
            *reinterpret_cast<short8*>(&As[r * 32 + sslot * 8]) = t;
        }
#pragma unroll
        for (int c = 0; c < 2; ++c) {
            int chunk = c * 256 + tid;
            int r = chunk >> 2, slot = chunk & 3;
            int gn = colBase + r;
            short8 t = {};
            if (gn < N)
                t = *reinterpret_cast<const short8*>(Bt + (size_t)gn * ldb + k0 + slot * 8);
            int sslot = slot ^ (r & 3);
            *reinterpret_cast<short8*>(&Bs[r * 32 + sslot * 8]) = t;
        }
        __syncthreads();

        short8 af[4], bfr[4];
#pragma unroll
        for (int m = 0; m < 4; ++m) {
            int r = wr + m * 16 + r16;
            af[m] = *reinterpret_cast<const short8*>(&As[r * 32 + (g ^ (r & 3)) * 8]);
        }
#pragma unroll
        for (int n = 0; n < 4; ++n) {
            int r = wc + n * 16 + r16;
            bfr[n] = *reinterpret_cast<const short8*>(&Bs[r * 32 + (g ^ (r & 3)) * 8]);
        }
#pragma unroll
        for (int m = 0; m < 4; ++m)
#pragma unroll
            for (int n = 0; n < 4; ++n)
                acc[m][n] = __builtin_amdgcn_mfma_f32_16x16x32_bf16(
                    af[m], bfr[n], acc[m][n], 0, 0, 0);
        __syncthreads();
    }

#pragma unroll
    for (int m = 0; m < 4; ++m) {
#pragma unroll
        for (int v = 0; v < 4; ++v) {
            int gr = rowBase + wr + m * 16 + g * 4 + v;
            if (gr >= M) continue;
#pragma unroll
            for (int n = 0; n < 4; ++n) {
                int gc = colBase + wc + n * 16 + r16;
                if (gc >= N) continue;
                float val = acc[m][n][v] + bias[gc];
                if (ACT == 1) val = (val > 20.f) ? val : log1pf(expf(val));
                C[(size_t)gr * ldc + gc] = val;
            }
        }
    }
}

// ---------------- depthwise causal conv (mean of 3) + SiLU -------------------
// BF: also emit bf16 mirror for the downstream GEMM
template <bool BF>
__global__ __launch_bounds__(256) void conv_silu(
    const float* __restrict__ xz, float* __restrict__ xconv,
    unsigned short* __restrict__ xconv_bf)
{
    int idx = blockIdx.x * blockDim.x + threadIdx.x;
    if (idx >= 4096 * 2048) return;
    int d = idx & 2047;
    int row = idx >> 11;        // row = b*2048 + l
    int l = row & 2047;

    float s = xz[(size_t)row * 4096 + d];
    if (l >= 1) s += xz[(size_t)(row - 1) * 4096 + d];
    if (l >= 2) s += xz[(size_t)(row - 2) * 4096 + d];
    s *= (1.f / 3.f);
    float sv = s / (1.f + __expf(-s));
    xconv[idx] = sv;
    if (BF) xconv_bf[idx] = f2bf(sv);
}

// ---------------- chunked selective scan, 4-states-per-lane ------------------
__global__ __launch_bounds__(256) void scan_passA(
    const float* __restrict__ dt,     // [4096][2048]
    const float* __restrict__ xdbl,   // [4096][96]
    const float* __restrict__ xconv,  // [4096][2048]
    const float* __restrict__ A_log,  // [2048][16]
    float* __restrict__ Pc,           // [2][16][2048][16]
    float* __restrict__ Sc)           // [2][16][2048][16]
{
    __shared__ float sBC[CT][32];
    const int tid  = threadIdx.x;
    const int bid  = blockIdx.x;         // 1024 = b(2) x c(16) x dg(32)
    const int dg   = bid & 31;
    const int c    = (bid >> 5) & 15;
    const int b    = bid >> 9;
    const int lane = tid & 63;
    const int wave = tid >> 6;
    const int chi  = lane & 15;
    const int ng   = lane >> 4;          // 0..3
    const int d    = dg * 64 + wave * 16 + chi;
    const size_t rowBase = (size_t)b * 2048 + (size_t)c * CT;

    for (int i = tid; i < CT * 8; i += 256) {
        int tt = i >> 3, q = i & 7;
        *reinterpret_cast<float4v*>(&sBC[tt][q * 4]) =
            *reinterpret_cast<const float4v*>(&xdbl[(rowBase + tt) * 96 + 64 + q * 4]);
    }
    __syncthreads();

    float4v Aval, h = {}, P = {1.f, 1.f, 1.f, 1.f};
#pragma unroll
    for (int j = 0; j < 4; ++j) Aval[j] = -expf(A_log[d * 16 + ng * 4 + j]);

    const float* pdt = dt + rowBase * 2048 + d;
    const float* px  = xconv + rowBase * 2048 + d;
    float dt_c = *pdt, x_c = *px;
    for (int t = 0; t < CT; ++t) {
        float dt_n = 0.f, x_n = 0.f;
        if (t + 1 < CT) { dt_n = pdt[2048]; x_n = px[2048]; }
        pdt += 2048; px += 2048;

        float4v Bv = *reinterpret_cast<const float4v*>(&sBC[t][ng * 4]);
        float u = dt_c * x_c;
#pragma unroll
        for (int j = 0; j < 4; ++j) {
            float dA = __expf(Aval[j] * dt_c);
            P[j] *= dA;
            h[j] = dA * h[j] + u * Bv[j];
        }
        dt_c = dt_n; x_c = x_n;
    }
    size_t o = (((size_t)(b * NCHUNK + c)) * 2048 + d) * 16 + ng * 4;
    *reinterpret_cast<float4v*>(&Pc[o]) = P;
    *reinterpret_cast<float4v*>(&Sc[o]) = h;
}

// Pass C: inter-chunk prefix from Pc/Sc, local rescan, fused skip+gate.
// WMODE 0: write f32 gated in-place over xconv (tier-2).
// WMODE 1: write bf16 gated to gated_bf (tier-1).
template <int WMODE>
__global__ __launch_bounds__(256) void scan_passC2(
    const float* __restrict__ dt,
    const float* __restrict__ xdbl,
    const float* __restrict__ xz,
    float* __restrict__ xconv,
    const float* __restrict__ A_log,
    const float* __restrict__ Dp,
    const float* __restrict__ Pc,
    const float* __restrict__ Sc,
    unsigned short* __restrict__ gated_bf)
{
    __shared__ float sBC[CT][32];
    const int tid  = threadIdx.x;
    const int bid  = blockIdx.x;
    const int dg   = bid & 31;
    const int c    = (bid >> 5) & 15;
    const int b    = bid >> 9;
    const int lane = tid & 63;
    const int wave = tid >> 6;
    const int chi  = lane & 15;
    const int ng   = lane >> 4;
    const int d    = dg * 64 + wave * 16 + chi;
    const size_t rowBase = (size_t)b * 2048 + (size_t)c * CT;

    for (int i = tid; i < CT * 8; i += 256) {
        int tt = i >> 3, q = i & 7;
        *reinterpret_cast<float4v*>(&sBC[tt][q * 4]) =
            *reinterpret_cast<const float4v*>(&xdbl[(rowBase + tt) * 96 + 64 + q * 4]);
    }
    __syncthreads();

    float4v Aval, h = {};
#pragma unroll
    for (int j = 0; j < 4; ++j) Aval[j] = -expf(A_log[d * 16 + ng * 4 + j]);
    const float Dval = Dp[d];

    for (int cp = 0; cp < c; ++cp) {
        size_t o = (((size_t)(b * NCHUNK + cp)) * 2048 + d) * 16 + ng * 4;
        float4v Pv = *reinterpret_cast<const float4v*>(&Pc[o]);
        float4v Sv = *reinterpret_cast<const float4v*>(&Sc[o]);
#pragma unroll
        for (int j = 0; j < 4; ++j) h[j] = Pv[j] * h[j] + Sv[j];
    }

    const float* pdt = dt + rowBase * 2048 + d;
    const float* px  = xconv + rowBase * 2048 + d;
    const float* pz  = xz + rowBase * 4096 + 2048 + d;
    float* pw        = xconv + rowBase * 2048 + d;
    unsigned short* pwb = gated_bf + rowBase * 2048 + d;
    float dt_c = *pdt, x_c = *px;

    for (int t = 0; t < CT; ++t) {
        float dt_n = 0.f, x_n = 0.f;
        if (t + 1 < CT) { dt_n = pdt[2048]; x_n = px[2048]; }
        pdt += 2048; px += 2048;

        float4v Bv = *reinterpret_cast<const float4v*>(&sBC[t][ng * 4]);
        float4v Cv = *reinterpret_cast<const float4v*>(&sBC[t][16 + ng * 4]);
        float u = dt_c * x_c;
        float p = 0.f;
#pragma unroll
        for (int j = 0; j < 4; ++j) {
            float dA = __expf(Aval[j] * dt_c);
            h[j] = dA * h[j] + u * Bv[j];
            p += h[j] * Cv[j];
        }
        p += __shfl_xor(p, 16);
        p += __shfl_xor(p, 32);

        if (ng == 0) {
            float y = p + x_c * Dval;
            float zv = *pz;
            float sz = zv / (1.f + __expf(-zv));
            float gv = y * sz;
            if (WMODE == 0) *pw = gv;
            else            *pwb = f2bf(gv);
        }
        pz += 4096; pw += 2048; pwb += 2048;
        dt_c = dt_n; x_c = x_n;
    }
}

// ---------------- monolithic scan (tier-3 fallback) --------------------------
__global__ __launch_bounds__(256) void scan_kernel(
    const float* __restrict__ dt, const float* __restrict__ xdbl,
    const float* __restrict__ xz, float* __restrict__ xconv,
    const float* __restrict__ A_log, const float* __restrict__ Dp)
{
    const int L = 2048, DI = 2048;
    const int n = threadIdx.x & 15;
    const int chi = threadIdx.x >> 4;
    const int b = blockIdx.x / 128;
    const int d = (blockIdx.x % 128) * 16 + chi;

    const float Aval = -expf(A_log[d * 16 + n]);
    const float Dval = Dp[d];
    float h = 0.f;
    const size_t rowBase = (size_t)b * L;

    float dt_c = dt[rowBase * DI + d];
    float x_c  = xconv[rowBase * DI + d];
    float B_c  = xdbl[rowBase * 96 + 64 + n];
    float C_c  = xdbl[rowBase * 96 + 80 + n];

    for (int t = 0; t < L; ++t) {
        size_t row = rowBase + t;
        float dt_n = 0.f, x_n = 0.f, B_n = 0.f, C_n = 0.f;
        if (t + 1 < L) {
            size_t rn = row + 1;
            dt_n = dt[rn * DI + d];
            x_n  = xconv[rn * DI + d];
            B_n  = xdbl[rn * 96 + 64 + n];
            C_n  = xdbl[rn * 96 + 80 + n];
        }
        float dA = __expf(Aval * dt_c);
        h = dA * h + (dt_c * x_c) * B_c;
        float p = h * C_c;
        p += __shfl_xor(p, 1, 16);
        p += __shfl_xor(p, 2, 16);
        p += __shfl_xor(p, 4, 16);
        p += __shfl_xor(p, 8, 16);
        if (n == 0) {
            float y = p + x_c * Dval;
            float zv = xz[row * 4096 + 2048 + d];
            float sz = zv / (1.f + __expf(-zv));
            xconv[row * DI + d] = y * sz;
        }
        dt_c = dt_n; x_c = x_n; B_c = B_n; C_c = C_n;
    }
}

extern "C" void kernel_launch(void* const* d_in, const int* in_sizes, int n_in,
                              void* d_out, int out_size, void* d_ws, size_t ws_size,
                              hipStream_t stream)
{
    const float* x     = (const float*)d_in[0];
    const float* W_in  = (const float*)d_in[1];
    const float* b_in  = (const float*)d_in[2];
    const float* W_x   = (const float*)d_in[3];
    const float* b_x   = (const float*)d_in[4];
    const float* W_dt  = (const float*)d_in[5];
    const float* b_dt  = (const float*)d_in[6];
    const float* A_log = (const float*)d_in[7];
    const float* Dp    = (const float*)d_in[8];
    const float* W_out = (const float*)d_in[9];
    const float* b_out = (const float*)d_in[10];
    float* out = (float*)d_out;

    float* ws    = (float*)d_ws;
    float* xz    = ws;                       // 16,777,216 f32
    float* xconv = xz + 16777216;            //  8,388,608 f32
    float* xdbl  = xconv + 8388608;          //    393,216 f32
    float* dtbuf = xdbl + 393216;            //  8,388,608 f32
    float* Pc    = dtbuf + 8388608;          //  1,048,576 f32
    float* Sc    = Pc + 1048576;             //  1,048,576 f32

    const size_t base_f32 = 16777216 + 8388608 + 393216 + 8388608;   // floats
    const size_t wshorts  = 4096 * 1024 + 96 * 2048 + 2048 * 64 + 1024 * 2048;
    const size_t bfshorts = 4096 * 1024 + 8388608 + 4096 * 64 + 8388608;
    const size_t needed_bf   = (base_f32 + 2 * 1048576) * 4 + (wshorts + bfshorts) * 2;
    const size_t needed_full = (base_f32 + 2 * 1048576) * 4 + wshorts * 2;
    const size_t needed_fall = base_f32 * 4 + wshorts * 2;

    const int tier = (ws_size >= needed_bf) ? 1 : (ws_size >= needed_full) ? 2
                   : (ws_size >= needed_fall) ? 3 : 0;
    if (tier == 0) return;   // tripwire: clean fail, never corrupt memory

    unsigned short* wbuf = (tier == 3) ? (unsigned short*)Pc
                                       : (unsigned short*)(Sc + 1048576);
    unsigned short* WinT  = wbuf;                  // [4096][1024] bf16
    unsigned short* WxT   = WinT  + 4096 * 1024;   // [96][2048]
    unsigned short* WdtT  = WxT   + 96 * 2048;     // [2048][64]
    unsigned short* WoutT = WdtT  + 2048 * 64;     // [1024][2048]
    // tier-1 bf16 mirrors
    unsigned short* x_bf     = WoutT + 1024 * 2048;   // [4096][1024]
    unsigned short* xconv_bf = x_bf + 4096 * 1024;    // [4096][2048]
    unsigned short* xdbl_bf  = xconv_bf + 8388608;    // [4096][64]
    unsigned short* gated_bf = xdbl_bf + 4096 * 64;   // [4096][2048]

    dim3 tblk(32, 8);
    transpose_bf16<<<dim3(128, 32), tblk, 0, stream>>>(W_in, WinT, 1024, 4096);
    transpose_bf16<<<dim3(3, 64),   tblk, 0, stream>>>(W_x,  WxT,  2048, 96);
    transpose_bf16<<<dim3(64, 2),   tblk, 0, stream>>>(W_dt, WdtT, 64, 2048);
    transpose_bf16<<<dim3(32, 64),  tblk, 0, stream>>>(W_out,WoutT,2048, 1024);

    dim3 blk(256);

    if (tier == 1) {
        // 0) x -> bf16
        cast_bf16<<<2048, blk, 0, stream>>>(x, x_bf, 4096 * 1024 / 8);

        // 1) xz = x @ W_in + b_in   (M=4096, N=4096, K=1024)
        gemm_bf<0, false><<<dim3(32, 32), blk, 0, stream>>>(
            x_bf, 1024, WinT, 1024, b_in, xz, 4096, nullptr, 0, 0, 4096, 1024);

        // 2) x_conv = silu(causal mean3(x_inner))  (+ bf16 mirror)
        conv_silu<true><<<(4096 * 2048 + 255) / 256, blk, 0, stream>>>(
            xz, xconv, xconv_bf);

        // 3) x_dbl = x_conv @ W_x + b_x   (N=96, K=2048; + bf16 dt-cols mirror)
        gemm_bf<0, true><<<dim3(1, 32), blk, 0, stream>>>(
            xconv_bf, 2048, WxT, 2048, b_x, xdbl, 96, xdbl_bf, 64, 64, 96, 2048);

        // 4) dt = softplus(x_dbl[:, :64] @ W_dt + b_dt)   (N=2048, K=64)
        gemm_bf<1, false><<<dim3(16, 32), blk, 0, stream>>>(
            xdbl_bf, 64, WdtT, 64, b_dt, dtbuf, 2048, nullptr, 0, 0, 2048, 64);

        // 5) chunked scan; gated written as bf16
        scan_passA<<<1024, blk, 0, stream>>>(dtbuf, xdbl, xconv, A_log, Pc, Sc);
        scan_passC2<1><<<1024, blk, 0, stream>>>(
            dtbuf, xdbl, xz, xconv, A_log, Dp, Pc, Sc, gated_bf);

        // 6) out = gated @ W_out + b_out   (N=1024, K=2048)
        gemm_bf<0, false><<<dim3(8, 32), blk, 0, stream>>>(
            gated_bf, 2048, WoutT, 2048, b_out, out, 1024, nullptr, 0, 0, 1024, 2048);
    } else {
        // tier-2/3: round-7 proven path (f32-A GEMMs)
        gemm_mfma<0><<<dim3(32, 32), blk, 0, stream>>>(
            x, 1024, WinT, 1024, b_in, xz, 4096, 4096, 4096, 1024);
        conv_silu<false><<<(4096 * 2048 + 255) / 256, blk, 0, stream>>>(
            xz, xconv, nullptr);
        gemm_mfma<0><<<dim3(1, 32), blk, 0, stream>>>(
            xconv, 2048, WxT, 2048, b_x, xdbl, 96, 4096, 96, 2048);
        gemm_mfma<1><<<dim3(16, 32), blk, 0, stream>>>(
            xdbl, 96, WdtT, 64, b_dt, dtbuf, 2048, 4096, 2048, 64);
        if (tier == 2) {
            scan_passA<<<1024, blk, 0, stream>>>(dtbuf, xdbl, xconv, A_log, Pc, Sc);
            scan_passC2<0><<<1024, blk, 0, stream>>>(
                dtbuf, xdbl, xz, xconv, A_log, Dp, Pc, Sc, (unsigned short*)xconv);
        } else {
            scan_kernel<<<256, blk, 0, stream>>>(dtbuf, xdbl, xz, xconv, A_log, Dp);
        }
        gemm_mfma<0><<<dim3(8, 32), blk, 0, stream>>>(
            xconv, 2048, WoutT, 2048, b_out, out, 1024, 4096, 1024, 2048);
    }
}

// Round 9
// 457.888 us; speedup vs baseline: 3.7518x; 1.0781x over previous
//
#include <hip/hip_runtime.h>
#include <hip/hip_bf16.h>

typedef __attribute__((ext_vector_type(8))) short short8;
typedef __attribute__((ext_vector_type(4))) float f32x4;
typedef __attribute__((ext_vector_type(4))) float float4v;

#define NCHUNK 32
#define CT 64   // chunk length (NCHUNK*CT == L == 2048)

static __device__ __forceinline__ unsigned short f2bf(float f) {
    union { float f; unsigned u; } v; v.f = f;
    unsigned r = v.u + 0x7fff + ((v.u >> 16) & 1);   // round-to-nearest-even
    return (unsigned short)(r >> 16);
}

static __device__ __forceinline__ void gld16(const unsigned short* g, unsigned short* l) {
    __builtin_amdgcn_global_load_lds(
        (const __attribute__((address_space(1))) void*)g,
        (__attribute__((address_space(3))) void*)l, 16, 0, 0);
}

// ---------------- f32 -> bf16 elementwise cast (8 elems/thread) --------------
__global__ __launch_bounds__(256) void cast_bf16(
    const float* __restrict__ in, unsigned short* __restrict__ out, int n8)
{
    int i = blockIdx.x * 256 + threadIdx.x;
    if (i >= n8) return;
    const float4v v0 = *reinterpret_cast<const float4v*>(in + (size_t)i * 8);
    const float4v v1 = *reinterpret_cast<const float4v*>(in + (size_t)i * 8 + 4);
    short8 t;
    t[0] = (short)f2bf(v0[0]); t[1] = (short)f2bf(v0[1]);
    t[2] = (short)f2bf(v0[2]); t[3] = (short)f2bf(v0[3]);
    t[4] = (short)f2bf(v1[0]); t[5] = (short)f2bf(v1[1]);
    t[6] = (short)f2bf(v1[2]); t[7] = (short)f2bf(v1[3]);
    *reinterpret_cast<short8*>(out + (size_t)i * 8) = t;
}

// ---------------- transpose + f32->bf16 convert: out[c][r] = bf16(in[r][c]) --
__global__ __launch_bounds__(256) void transpose_bf16(
    const float* __restrict__ in, unsigned short* __restrict__ out, int R, int Cc)
{
    __shared__ float tile[32][33];
    int c0 = blockIdx.x * 32, r0 = blockIdx.y * 32;
    int tx = threadIdx.x, ty = threadIdx.y;      // 32 x 8
#pragma unroll
    for (int i = 0; i < 32; i += 8) {
        int r = r0 + ty + i, c = c0 + tx;
        tile[ty + i][tx] = (r < R && c < Cc) ? in[(size_t)r * Cc + c] : 0.f;
    }
    __syncthreads();
#pragma unroll
    for (int i = 0; i < 32; i += 8) {
        int c = c0 + ty + i, r = r0 + tx;        // out[c][r]
        if (c < Cc && r < R) out[(size_t)c * R + r] = f2bf(tile[tx][ty + i]);
    }
}

// ---------------- bf16 MFMA GEMM (m97 structure): C = A @ Bt^T + bias --------
// A: bf16 [M][lda], Bt: bf16 [N][ldb]. Tile 128x128, BK=32, 4 waves.
// global_load_lds width-16 staging, linear LDS, 8 ds_read_b128 + 16 MFMA/wave.
// M must be a multiple of 128; N may be < tile (guarded in epilogue; B OOB
// rows read adjacent ws memory - finite bf16, never stored).
// AUX: also write bf16(val) to Cbf[gr*ldcbf+gc] for gc < ncbf.
template <int ACT, bool AUX>
__global__ __launch_bounds__(256) void gemm_bf(
    const unsigned short* __restrict__ A, int lda,
    const unsigned short* __restrict__ Bt, int ldb,
    const float* __restrict__ bias,
    float* __restrict__ C, int ldc,
    unsigned short* __restrict__ Cbf, int ldcbf, int ncbf,
    int N, int K)
{
    __shared__ __align__(16) unsigned short As[128 * 32];
    __shared__ __align__(16) unsigned short Bs[128 * 32];

    const int tid  = threadIdx.x;
    const int lane = tid & 63;
    const int wave = tid >> 6;
    const int g    = lane >> 4;        // k-group 0..3
    const int r16  = lane & 15;
    const int wr   = (wave >> 1) * 64;
    const int wc   = (wave & 1) * 64;
    const int rowBase = blockIdx.y * 128;
    const int colBase = blockIdx.x * 128;

    const int e0 = tid * 8;
    const int e1 = (256 + tid) * 8;
    const int r0 = e0 >> 5, c0 = e0 & 31;
    const int r1 = e1 >> 5, c1 = e1 & 31;
    const unsigned short* a0 = A + (size_t)(rowBase + r0) * lda + c0;
    const unsigned short* a1 = A + (size_t)(rowBase + r1) * lda + c1;
    const unsigned short* b0 = Bt + (size_t)(colBase + r0) * ldb + c0;
    const unsigned short* b1 = Bt + (size_t)(colBase + r1) * ldb + c1;

    f32x4 acc[4][4] = {};

    for (int k0 = 0; k0 < K; k0 += 32) {
        gld16(a0 + k0, As + e0);
        gld16(a1 + k0, As + e1);
        gld16(b0 + k0, Bs + e0);
        gld16(b1 + k0, Bs + e1);
        __syncthreads();

        short8 af[4], bfr[4];
#pragma unroll
        for (int m = 0; m < 4; ++m)
            af[m] = *reinterpret_cast<const short8*>(&As[(wr + m * 16 + r16) * 32 + g * 8]);
#pragma unroll
        for (int n = 0; n < 4; ++n)
            bfr[n] = *reinterpret_cast<const short8*>(&Bs[(wc + n * 16 + r16) * 32 + g * 8]);
#pragma unroll
        for (int m = 0; m < 4; ++m)
#pragma unroll
            for (int n = 0; n < 4; ++n)
                acc[m][n] = __builtin_amdgcn_mfma_f32_16x16x32_bf16(
                    af[m], bfr[n], acc[m][n], 0, 0, 0);
        __syncthreads();
    }

    // epilogue: D row = g*4 + v (A-side), col = r16 (B-side)  [m89/m91]
#pragma unroll
    for (int m = 0; m < 4; ++m) {
#pragma unroll
        for (int v = 0; v < 4; ++v) {
            int gr = rowBase + wr + m * 16 + g * 4 + v;
#pragma unroll
            for (int n = 0; n < 4; ++n) {
                int gc = colBase + wc + n * 16 + r16;
                if (gc >= N) continue;
                float val = acc[m][n][v] + bias[gc];
                if (ACT == 1) val = (val > 20.f) ? val : log1pf(expf(val));
                C[(size_t)gr * ldc + gc] = val;
                if (AUX && gc < ncbf)
                    Cbf[(size_t)gr * ldcbf + gc] = f2bf(val);
            }
        }
    }
}

// ---------------- f32-A MFMA GEMM (tier-2 fallback; round-7 proven) ----------
template <int ACT>
__global__ __launch_bounds__(256) void gemm_mfma(
    const float* __restrict__ A, int lda,
    const unsigned short* __restrict__ Bt, int ldb,
    const float* __restrict__ bias,
    float* __restrict__ C, int ldc,
    int M, int N, int K)
{
    __shared__ unsigned short As[128 * 32];
    __shared__ unsigned short Bs[128 * 32];

    const int tid  = threadIdx.x;
    const int lane = tid & 63;
    const int wave = tid >> 6;
    const int g    = lane >> 4;
    const int r16  = lane & 15;
    const int wr   = (wave >> 1) * 64;
    const int wc   = (wave & 1) * 64;
    const int rowBase = blockIdx.y * 128;
    const int colBase = blockIdx.x * 128;

    f32x4 acc[4][4] = {};

    for (int k0 = 0; k0 < K; k0 += 32) {
#pragma unroll
        for (int c = 0; c < 2; ++c) {
            int chunk = c * 256 + tid;
            int r = chunk >> 2, slot = chunk & 3;
            int gr = rowBase + r;
            short8 t = {};
            if (gr < M) {
                const float* src = A + (size_t)gr * lda + k0 + slot * 8;
                float4v v0 = *reinterpret_cast<const float4v*>(src);
                float4v v1 = *reinterpret_cast<const float4v*>(src + 4);
                t[0] = (short)f2bf(v0[0]); t[1] = (short)f2bf(v0[1]);
                t[2] = (short)f2bf(v0[2]); t[3] = (short)f2bf(v0[3]);
                t[4] = (short)f2bf(v1[0]); t[5] = (short)f2bf(v1[1]);
                t[6] = (short)f2bf(v1[2]); t[7] = (short)f2bf(v1[3]);
            }
            int sslot = slot ^ (r & 3);
            *reinterpret_cast<short8*>(&As[r * 32 + sslot * 8]) = t;
        }
#pragma unroll
        for (int c = 0; c < 2; ++c) {
            int chunk = c * 256 + tid;
            int r = chunk >> 2, slot = chunk & 3;
            int gn = colBase + r;
            short8 t = {};
            if (gn < N)
                t = *reinterpret_cast<const short8*>(Bt + (size_t)gn * ldb + k0 + slot * 8);
            int sslot = slot ^ (r & 3);
            *reinterpret_cast<short8*>(&Bs[r * 32 + sslot * 8]) = t;
        }
        __syncthreads();

        short8 af[4], bfr[4];
#pragma unroll
        for (int m = 0; m < 4; ++m) {
            int r = wr + m * 16 + r16;
            af[m] = *reinterpret_cast<const short8*>(&As[r * 32 + (g ^ (r & 3)) * 8]);
        }
#pragma unroll
        for (int n = 0; n < 4; ++n) {
            int r = wc + n * 16 + r16;
            bfr[n] = *reinterpret_cast<const short8*>(&Bs[r * 32 + (g ^ (r & 3)) * 8]);
        }
#pragma unroll
        for (int m = 0; m < 4; ++m)
#pragma unroll
            for (int n = 0; n < 4; ++n)
                acc[m][n] = __builtin_amdgcn_mfma_f32_16x16x32_bf16(
                    af[m], bfr[n], acc[m][n], 0, 0, 0);
        __syncthreads();
    }

#pragma unroll
    for (int m = 0; m < 4; ++m) {
#pragma unroll
        for (int v = 0; v < 4; ++v) {
            int gr = rowBase + wr + m * 16 + g * 4 + v;
            if (gr >= M) continue;
#pragma unroll
            for (int n = 0; n < 4; ++n) {
                int gc = colBase + wc + n * 16 + r16;
                if (gc >= N) continue;
                float val = acc[m][n][v] + bias[gc];
                if (ACT == 1) val = (val > 20.f) ? val : log1pf(expf(val));
                C[(size_t)gr * ldc + gc] = val;
            }
        }
    }
}

// ---------------- depthwise causal conv (mean of 3) + SiLU -------------------
template <bool BF>
__global__ __launch_bounds__(256) void conv_silu(
    const float* __restrict__ xz, float* __restrict__ xconv,
    unsigned short* __restrict__ xconv_bf)
{
    int idx = blockIdx.x * blockDim.x + threadIdx.x;
    if (idx >= 4096 * 2048) return;
    int d = idx & 2047;
    int row = idx >> 11;        // row = b*2048 + l
    int l = row & 2047;

    float s = xz[(size_t)row * 4096 + d];
    if (l >= 1) s += xz[(size_t)(row - 1) * 4096 + d];
    if (l >= 2) s += xz[(size_t)(row - 2) * 4096 + d];
    s *= (1.f / 3.f);
    float sv = s / (1.f + __expf(-s));
    xconv[idx] = sv;
    if (BF) xconv_bf[idx] = f2bf(sv);
}

// ---------------- chunked selective scan, 4-states-per-lane ------------------
// Lane: chi = lane&15 (channel), ng = lane>>4 (state quad). Block covers 64
// channels x CT timesteps. Grid: 2048 = b(2) x c(32) x dg(32).

// Pass A: per chunk with h_in = 0: P = prod(dA) (x4), S = local final state.
__global__ __launch_bounds__(256) void scan_passA(
    const float* __restrict__ dt,     // [4096][2048]
    const float* __restrict__ xdbl,   // [4096][96]
    const float* __restrict__ xconv,  // [4096][2048]
    const float* __restrict__ A_log,  // [2048][16]
    float* __restrict__ Pc,           // [2][32][2048][16]
    float* __restrict__ Sc)           // [2][32][2048][16]
{
    __shared__ float sBC[CT][32];
    const int tid  = threadIdx.x;
    const int bid  = blockIdx.x;
    const int dg   = bid & 31;
    const int c    = (bid >> 5) & 31;
    const int b    = bid >> 10;
    const int lane = tid & 63;
    const int wave = tid >> 6;
    const int chi  = lane & 15;
    const int ng   = lane >> 4;          // 0..3
    const int d    = dg * 64 + wave * 16 + chi;
    const size_t rowBase = (size_t)b * 2048 + (size_t)c * CT;

    for (int i = tid; i < CT * 8; i += 256) {
        int tt = i >> 3, q = i & 7;
        *reinterpret_cast<float4v*>(&sBC[tt][q * 4]) =
            *reinterpret_cast<const float4v*>(&xdbl[(rowBase + tt) * 96 + 64 + q * 4]);
    }
    __syncthreads();

    float4v Aval, h = {}, P = {1.f, 1.f, 1.f, 1.f};
#pragma unroll
    for (int j = 0; j < 4; ++j) Aval[j] = -expf(A_log[d * 16 + ng * 4 + j]);

    const float* pdt = dt + rowBase * 2048 + d;
    const float* px  = xconv + rowBase * 2048 + d;
    float dt_c = *pdt, x_c = *px;
    for (int t = 0; t < CT; ++t) {
        float dt_n = 0.f, x_n = 0.f;
        if (t + 1 < CT) { dt_n = pdt[2048]; x_n = px[2048]; }
        pdt += 2048; px += 2048;

        float4v Bv = *reinterpret_cast<const float4v*>(&sBC[t][ng * 4]);
        float u = dt_c * x_c;
#pragma unroll
        for (int j = 0; j < 4; ++j) {
            float dA = __expf(Aval[j] * dt_c);
            P[j] *= dA;
            h[j] = dA * h[j] + u * Bv[j];
        }
        dt_c = dt_n; x_c = x_n;
    }
    size_t o = (((size_t)(b * NCHUNK + c)) * 2048 + d) * 16 + ng * 4;
    *reinterpret_cast<float4v*>(&Pc[o]) = P;
    *reinterpret_cast<float4v*>(&Sc[o]) = h;
}

// Pass B: sequential over chunks, in place: Pc[c] <- state at START of chunk c.
// 16384 threads, each owns a (b, d, state-quad) slice across all chunks.
__global__ __launch_bounds__(256) void scan_passB(
    float* __restrict__ Pc, const float* __restrict__ Sc)
{
    int idx = blockIdx.x * 256 + threadIdx.x;   // 0..16383
    int ng  = idx & 3;
    int d   = (idx >> 2) & 2047;
    int b   = idx >> 13;
    float4v h = {};
#pragma unroll
    for (int c = 0; c < NCHUNK; ++c) {
        size_t o = (((size_t)(b * NCHUNK + c)) * 2048 + d) * 16 + ng * 4;
        float4v Pv = *reinterpret_cast<const float4v*>(&Pc[o]);
        float4v Sv = *reinterpret_cast<const float4v*>(&Sc[o]);
        *reinterpret_cast<float4v*>(&Pc[o]) = h;
#pragma unroll
        for (int j = 0; j < 4; ++j) h[j] = Pv[j] * h[j] + Sv[j];
    }
}

// Pass C: local rescan seeded with Pc (= chunk-start state after passB);
// fused skip + gate; writes bf16 gated.
__global__ __launch_bounds__(256) void scan_passC2(
    const float* __restrict__ dt,
    const float* __restrict__ xdbl,
    const float* __restrict__ xz,
    const float* __restrict__ xconv,
    const float* __restrict__ A_log,
    const float* __restrict__ Dp,
    const float* __restrict__ Pc,     // start states (post-passB)
    unsigned short* __restrict__ gated_bf)
{
    __shared__ float sBC[CT][32];
    const int tid  = threadIdx.x;
    const int bid  = blockIdx.x;
    const int dg   = bid & 31;
    const int c    = (bid >> 5) & 31;
    const int b    = bid >> 10;
    const int lane = tid & 63;
    const int wave = tid >> 6;
    const int chi  = lane & 15;
    const int ng   = lane >> 4;
    const int d    = dg * 64 + wave * 16 + chi;
    const size_t rowBase = (size_t)b * 2048 + (size_t)c * CT;

    for (int i = tid; i < CT * 8; i += 256) {
        int tt = i >> 3, q = i & 7;
        *reinterpret_cast<float4v*>(&sBC[tt][q * 4]) =
            *reinterpret_cast<const float4v*>(&xdbl[(rowBase + tt) * 96 + 64 + q * 4]);
    }
    __syncthreads();

    float4v Aval;
#pragma unroll
    for (int j = 0; j < 4; ++j) Aval[j] = -expf(A_log[d * 16 + ng * 4 + j]);
    const float Dval = Dp[d];

    float4v h = *reinterpret_cast<const float4v*>(
        &Pc[(((size_t)(b * NCHUNK + c)) * 2048 + d) * 16 + ng * 4]);

    const float* pdt = dt + rowBase * 2048 + d;
    const float* px  = xconv + rowBase * 2048 + d;
    const float* pz  = xz + rowBase * 4096 + 2048 + d;
    unsigned short* pwb = gated_bf + rowBase * 2048 + d;
    float dt_c = *pdt, x_c = *px;

    for (int t = 0; t < CT; ++t) {
        float dt_n = 0.f, x_n = 0.f;
        if (t + 1 < CT) { dt_n = pdt[2048]; x_n = px[2048]; }
        pdt += 2048; px += 2048;

        float4v Bv = *reinterpret_cast<const float4v*>(&sBC[t][ng * 4]);
        float4v Cv = *reinterpret_cast<const float4v*>(&sBC[t][16 + ng * 4]);
        float u = dt_c * x_c;
        float p = 0.f;
#pragma unroll
        for (int j = 0; j < 4; ++j) {
            float dA = __expf(Aval[j] * dt_c);
            h[j] = dA * h[j] + u * Bv[j];
            p += h[j] * Cv[j];
        }
        p += __shfl_xor(p, 16);
        p += __shfl_xor(p, 32);

        if (ng == 0) {
            float y = p + x_c * Dval;
            float zv = *pz;
            float sz = zv / (1.f + __expf(-zv));
            *pwb = f2bf(y * sz);
        }
        pz += 4096; pwb += 2048;
        dt_c = dt_n; x_c = x_n;
    }
}

// ---------------- monolithic scan (tier-2 fallback; round-4 proven) ----------
__global__ __launch_bounds__(256) void scan_kernel(
    const float* __restrict__ dt, const float* __restrict__ xdbl,
    const float* __restrict__ xz, float* __restrict__ xconv,
    const float* __restrict__ A_log, const float* __restrict__ Dp)
{
    const int L = 2048, DI = 2048;
    const int n = threadIdx.x & 15;
    const int chi = threadIdx.x >> 4;
    const int b = blockIdx.x / 128;
    const int d = (blockIdx.x % 128) * 16 + chi;

    const float Aval = -expf(A_log[d * 16 + n]);
    const float Dval = Dp[d];
    float h = 0.f;
    const size_t rowBase = (size_t)b * L;

    float dt_c = dt[rowBase * DI + d];
    float x_c  = xconv[rowBase * DI + d];
    float B_c  = xdbl[rowBase * 96 + 64 + n];
    float C_c  = xdbl[rowBase * 96 + 80 + n];

    for (int t = 0; t < L; ++t) {
        size_t row = rowBase + t;
        float dt_n = 0.f, x_n = 0.f, B_n = 0.f, C_n = 0.f;
        if (t + 1 < L) {
            size_t rn = row + 1;
            dt_n = dt[rn * DI + d];
            x_n  = xconv[rn * DI + d];
            B_n  = xdbl[rn * 96 + 64 + n];
            C_n  = xdbl[rn * 96 + 80 + n];
        }
        float dA = __expf(Aval * dt_c);
        h = dA * h + (dt_c * x_c) * B_c;
        float p = h * C_c;
        p += __shfl_xor(p, 1, 16);
        p += __shfl_xor(p, 2, 16);
        p += __shfl_xor(p, 4, 16);
        p += __shfl_xor(p, 8, 16);
        if (n == 0) {
            float y = p + x_c * Dval;
            float zv = xz[row * 4096 + 2048 + d];
            float sz = zv / (1.f + __expf(-zv));
            xconv[row * DI + d] = y * sz;
        }
        dt_c = dt_n; x_c = x_n; B_c = B_n; C_c = C_n;
    }
}

extern "C" void kernel_launch(void* const* d_in, const int* in_sizes, int n_in,
                              void* d_out, int out_size, void* d_ws, size_t ws_size,
                              hipStream_t stream)
{
    const float* x     = (const float*)d_in[0];
    const float* W_in  = (const float*)d_in[1];
    const float* b_in  = (const float*)d_in[2];
    const float* W_x   = (const float*)d_in[3];
    const float* b_x   = (const float*)d_in[4];
    const float* W_dt  = (const float*)d_in[5];
    const float* b_dt  = (const float*)d_in[6];
    const float* A_log = (const float*)d_in[7];
    const float* Dp    = (const float*)d_in[8];
    const float* W_out = (const float*)d_in[9];
    const float* b_out = (const float*)d_in[10];
    float* out = (float*)d_out;

    float* ws    = (float*)d_ws;
    float* xz    = ws;                       // 16,777,216 f32
    float* xconv = xz + 16777216;            //  8,388,608 f32
    float* xdbl  = xconv + 8388608;          //    393,216 f32
    float* dtbuf = xdbl + 393216;            //  8,388,608 f32
    float* Pc    = dtbuf + 8388608;          //  2,097,152 f32
    float* Sc    = Pc + 2097152;             //  2,097,152 f32

    const size_t base_f32 = 16777216 + 8388608 + 393216 + 8388608;   // floats
    const size_t wshorts  = 4096 * 1024 + 96 * 2048 + 2048 * 64 + 1024 * 2048;
    const size_t bfshorts = 4096 * 1024 + 8388608 + 4096 * 64;       // x, xconv(=gated), xdbl
    const size_t needed_t1 = (base_f32 + 2 * 2097152) * 4 + (wshorts + bfshorts) * 2;
    const size_t needed_t2 = base_f32 * 4 + wshorts * 2;

    const int tier = (ws_size >= needed_t1) ? 1 : (ws_size >= needed_t2) ? 2 : 0;
    if (tier == 0) return;   // tripwire: clean fail, never corrupt memory

    unsigned short* wbuf = (tier == 1) ? (unsigned short*)(Sc + 2097152)
                                       : (unsigned short*)Pc;
    unsigned short* WinT  = wbuf;                  // [4096][1024] bf16
    unsigned short* WxT   = WinT  + 4096 * 1024;   // [96][2048]
    unsigned short* WdtT  = WxT   + 96 * 2048;     // [2048][64]
    unsigned short* WoutT = WdtT  + 2048 * 64;     // [1024][2048]
    // tier-1 bf16 mirrors; gated_bf aliases xconv_bf (GEMM3 done before passC2)
    unsigned short* x_bf     = WoutT + 1024 * 2048;   // [4096][1024]
    unsigned short* xconv_bf = x_bf + 4096 * 1024;    // [4096][2048]
    unsigned short* xdbl_bf  = xconv_bf + 8388608;    // [4096][64]
    unsigned short* gated_bf = xconv_bf;              // alias (safe: see order)

    dim3 tblk(32, 8);
    transpose_bf16<<<dim3(128, 32), tblk, 0, stream>>>(W_in, WinT, 1024, 4096);
    transpose_bf16<<<dim3(3, 64),   tblk, 0, stream>>>(W_x,  WxT,  2048, 96);
    transpose_bf16<<<dim3(64, 2),   tblk, 0, stream>>>(W_dt, WdtT, 64, 2048);
    transpose_bf16<<<dim3(32, 64),  tblk, 0, stream>>>(W_out,WoutT,2048, 1024);

    dim3 blk(256);

    if (tier == 1) {
        // 0) x -> bf16
        cast_bf16<<<2048, blk, 0, stream>>>(x, x_bf, 4096 * 1024 / 8);

        // 1) xz = x @ W_in + b_in   (M=4096, N=4096, K=1024)
        gemm_bf<0, false><<<dim3(32, 32), blk, 0, stream>>>(
            x_bf, 1024, WinT, 1024, b_in, xz, 4096, nullptr, 0, 0, 4096, 1024);

        // 2) x_conv = silu(causal mean3(x_inner))  (+ bf16 mirror)
        conv_silu<true><<<(4096 * 2048 + 255) / 256, blk, 0, stream>>>(
            xz, xconv, xconv_bf);

        // 3) x_dbl = x_conv @ W_x + b_x   (N=96, K=2048; + bf16 dt-cols mirror)
        gemm_bf<0, true><<<dim3(1, 32), blk, 0, stream>>>(
            xconv_bf, 2048, WxT, 2048, b_x, xdbl, 96, xdbl_bf, 64, 64, 96, 2048);

        // 4) dt = softplus(x_dbl[:, :64] @ W_dt + b_dt)   (N=2048, K=64)
        gemm_bf<1, false><<<dim3(16, 32), blk, 0, stream>>>(
            xdbl_bf, 64, WdtT, 64, b_dt, dtbuf, 2048, nullptr, 0, 0, 2048, 64);

        // 5) chunked scan: A (local), B (chunk prefix, in-place), C (rescan+gate)
        scan_passA<<<2048, blk, 0, stream>>>(dtbuf, xdbl, xconv, A_log, Pc, Sc);
        scan_passB<<<64, blk, 0, stream>>>(Pc, Sc);
        scan_passC2<<<2048, blk, 0, stream>>>(
            dtbuf, xdbl, xz, xconv, A_log, Dp, Pc, gated_bf);

        // 6) out = gated @ W_out + b_out   (N=1024, K=2048)
        gemm_bf<0, false><<<dim3(8, 32), blk, 0, stream>>>(
            gated_bf, 2048, WoutT, 2048, b_out, out, 1024, nullptr, 0, 0, 1024, 2048);
    } else {
        // tier-2: f32-A GEMMs + monolithic scan (proven standalone)
        gemm_mfma<0><<<dim3(32, 32), blk, 0, stream>>>(
            x, 1024, WinT, 1024, b_in, xz, 4096, 4096, 4096, 1024);
        conv_silu<false><<<(4096 * 2048 + 255) / 256, blk, 0, stream>>>(
            xz, xconv, nullptr);
        gemm_mfma<0><<<dim3(1, 32), blk, 0, stream>>>(
            xconv, 2048, WxT, 2048, b_x, xdbl, 96, 4096, 96, 2048);
        gemm_mfma<1><<<dim3(16, 32), blk, 0, stream>>>(
            xdbl, 96, WdtT, 64, b_dt, dtbuf, 2048, 4096, 2048, 64);
        scan_kernel<<<256, blk, 0, stream>>>(dtbuf, xdbl, xz, xconv, A_log, Dp);
        gemm_mfma<0><<<dim3(8, 32), blk, 0, stream>>>(
            xconv, 2048, WoutT, 2048, b_out, out, 1024, 4096, 1024, 2048);
    }
}

// Round 10
// 440.187 us; speedup vs baseline: 3.9027x; 1.0402x over previous
//
#include <hip/hip_runtime.h>
#include <hip/hip_bf16.h>

typedef __attribute__((ext_vector_type(8))) short short8;
typedef __attribute__((ext_vector_type(4))) float f32x4;
typedef __attribute__((ext_vector_type(4))) float float4v;

#define NCHUNK 32
#define CT 64   // chunk length (NCHUNK*CT == L == 2048)

static __device__ __forceinline__ unsigned short f2bf(float f) {
    union { float f; unsigned u; } v; v.f = f;
    unsigned r = v.u + 0x7fff + ((v.u >> 16) & 1);   // round-to-nearest-even
    return (unsigned short)(r >> 16);
}

static __device__ __forceinline__ void gld16(const unsigned short* g, unsigned short* l) {
    __builtin_amdgcn_global_load_lds(
        (const __attribute__((address_space(1))) void*)g,
        (__attribute__((address_space(3))) void*)l, 16, 0, 0);
}

// ---------------- f32 -> bf16 elementwise cast (8 elems/thread) --------------
__global__ __launch_bounds__(256) void cast_bf16(
    const float* __restrict__ in, unsigned short* __restrict__ out, int n8)
{
    int i = blockIdx.x * 256 + threadIdx.x;
    if (i >= n8) return;
    const float4v v0 = *reinterpret_cast<const float4v*>(in + (size_t)i * 8);
    const float4v v1 = *reinterpret_cast<const float4v*>(in + (size_t)i * 8 + 4);
    short8 t;
    t[0] = (short)f2bf(v0[0]); t[1] = (short)f2bf(v0[1]);
    t[2] = (short)f2bf(v0[2]); t[3] = (short)f2bf(v0[3]);
    t[4] = (short)f2bf(v1[0]); t[5] = (short)f2bf(v1[1]);
    t[6] = (short)f2bf(v1[2]); t[7] = (short)f2bf(v1[3]);
    *reinterpret_cast<short8*>(out + (size_t)i * 8) = t;
}

// ---------------- transpose + f32->bf16 convert: out[c][r] = bf16(in[r][c]) --
__global__ __launch_bounds__(256) void transpose_bf16(
    const float* __restrict__ in, unsigned short* __restrict__ out, int R, int Cc)
{
    __shared__ float tile[32][33];
    int c0 = blockIdx.x * 32, r0 = blockIdx.y * 32;
    int tx = threadIdx.x, ty = threadIdx.y;      // 32 x 8
#pragma unroll
    for (int i = 0; i < 32; i += 8) {
        int r = r0 + ty + i, c = c0 + tx;
        tile[ty + i][tx] = (r < R && c < Cc) ? in[(size_t)r * Cc + c] : 0.f;
    }
    __syncthreads();
#pragma unroll
    for (int i = 0; i < 32; i += 8) {
        int c = c0 + ty + i, r = r0 + tx;        // out[c][r]
        if (c < Cc && r < R) out[(size_t)c * R + r] = f2bf(tile[tx][ty + i]);
    }
}

// ---------------- bf16 MFMA GEMM, double-buffered (T3 minimum 2-phase) -------
// A: bf16 [M][lda], Bt: bf16 [N][ldb]. Tile 128x128, BK=32, 4 waves.
// STAGE(next) issued BEFORE compute(cur); one __syncthreads per K-step covers
// both "loads arrived" (vmcnt drain) and "all waves done reading cur".
// PART (split-K): blockIdx.x = split s; computes k in [s*kLen, (s+1)*kLen),
// writes raw partial sums (no bias/ACT) to C + s*partStride, colBase=0.
template <int ACT, bool PART>
__global__ __launch_bounds__(256) void gemm_bf(
    const unsigned short* __restrict__ A, int lda,
    const unsigned short* __restrict__ Bt, int ldb,
    const float* __restrict__ bias,
    float* __restrict__ C, int ldc,
    int N, int kLen, size_t partStride)
{
    __shared__ __align__(16) unsigned short As[2][128 * 32];
    __shared__ __align__(16) unsigned short Bs[2][128 * 32];

    const int tid  = threadIdx.x;
    const int lane = tid & 63;
    const int wave = tid >> 6;
    const int g    = lane >> 4;        // k-group 0..3
    const int r16  = lane & 15;
    const int wr   = (wave >> 1) * 64;
    const int wc   = (wave & 1) * 64;
    const int rowBase = blockIdx.y * 128;
    const int colBase = PART ? 0 : blockIdx.x * 128;
    const int kOff    = PART ? blockIdx.x * kLen : 0;
    if (PART) C += partStride * blockIdx.x;

    const int e0 = tid * 8;
    const int e1 = (256 + tid) * 8;
    const int r0 = e0 >> 5, c0 = e0 & 31;
    const int r1 = e1 >> 5, c1 = e1 & 31;
    const unsigned short* a0 = A + (size_t)(rowBase + r0) * lda + c0 + kOff;
    const unsigned short* a1 = A + (size_t)(rowBase + r1) * lda + c1 + kOff;
    const unsigned short* b0 = Bt + (size_t)(colBase + r0) * ldb + c0 + kOff;
    const unsigned short* b1 = Bt + (size_t)(colBase + r1) * ldb + c1 + kOff;

    f32x4 acc[4][4] = {};

    // prologue: stage step 0 into buffer 0
    gld16(a0, As[0] + e0);
    gld16(a1, As[0] + e1);
    gld16(b0, Bs[0] + e0);
    gld16(b1, Bs[0] + e1);
    __syncthreads();

    const int nSteps = kLen >> 5;
    int cur = 0;
    for (int s = 0; s < nSteps; ++s) {
        if (s + 1 < nSteps) {                 // issue next-tile loads (async)
            int ko = (s + 1) * 32;
            gld16(a0 + ko, As[cur ^ 1] + e0);
            gld16(a1 + ko, As[cur ^ 1] + e1);
            gld16(b0 + ko, Bs[cur ^ 1] + e0);
            gld16(b1 + ko, Bs[cur ^ 1] + e1);
        }
        short8 af[4], bfr[4];
#pragma unroll
        for (int m = 0; m < 4; ++m)
            af[m] = *reinterpret_cast<const short8*>(&As[cur][(wr + m * 16 + r16) * 32 + g * 8]);
#pragma unroll
        for (int n = 0; n < 4; ++n)
            bfr[n] = *reinterpret_cast<const short8*>(&Bs[cur][(wc + n * 16 + r16) * 32 + g * 8]);
#pragma unroll
        for (int m = 0; m < 4; ++m)
#pragma unroll
            for (int n = 0; n < 4; ++n)
                acc[m][n] = __builtin_amdgcn_mfma_f32_16x16x32_bf16(
                    af[m], bfr[n], acc[m][n], 0, 0, 0);
        __syncthreads();   // drains vmcnt (next tile ready) + readers done with cur
        cur ^= 1;
    }

    // epilogue: D row = g*4 + v (A-side), col = r16 (B-side)  [m89/m91]
#pragma unroll
    for (int m = 0; m < 4; ++m) {
#pragma unroll
        for (int v = 0; v < 4; ++v) {
            int gr = rowBase + wr + m * 16 + g * 4 + v;
#pragma unroll
            for (int n = 0; n < 4; ++n) {
                int gc = colBase + wc + n * 16 + r16;
                if (gc >= N) continue;
                float val = acc[m][n][v];
                if (!PART) {
                    val += bias[gc];
                    if (ACT == 1) val = (val > 20.f) ? val : log1pf(expf(val));
                }
                C[(size_t)gr * ldc + gc] = val;
            }
        }
    }
}

// ---------------- split-K combine for GEMM3: sum 4 partials + bias -----------
// also emits bf16 mirror of the dt-rank cols (0..63) for GEMM4.
__global__ __launch_bounds__(256) void combine3(
    const float* __restrict__ Cpart, const float* __restrict__ b_x,
    float* __restrict__ xdbl, unsigned short* __restrict__ xdbl_bf)
{
    int idx = blockIdx.x * 256 + threadIdx.x;
    if (idx >= 4096 * 96) return;
    const int S = 4096 * 96;
    float v = Cpart[idx] + Cpart[idx + S] + Cpart[idx + 2 * S] + Cpart[idx + 3 * S];
    int row = idx / 96;
    int col = idx - row * 96;
    v += b_x[col];
    xdbl[idx] = v;
    if (col < 64) xdbl_bf[row * 64 + col] = f2bf(v);
}

// ---------------- f32-A MFMA GEMM (tier-2 fallback; round-7 proven) ----------
template <int ACT>
__global__ __launch_bounds__(256) void gemm_mfma(
    const float* __restrict__ A, int lda,
    const unsigned short* __restrict__ Bt, int ldb,
    const float* __restrict__ bias,
    float* __restrict__ C, int ldc,
    int M, int N, int K)
{
    __shared__ unsigned short As[128 * 32];
    __shared__ unsigned short Bs[128 * 32];

    const int tid  = threadIdx.x;
    const int lane = tid & 63;
    const int wave = tid >> 6;
    const int g    = lane >> 4;
    const int r16  = lane & 15;
    const int wr   = (wave >> 1) * 64;
    const int wc   = (wave & 1) * 64;
    const int rowBase = blockIdx.y * 128;
    const int colBase = blockIdx.x * 128;

    f32x4 acc[4][4] = {};

    for (int k0 = 0; k0 < K; k0 += 32) {
#pragma unroll
        for (int c = 0; c < 2; ++c) {
            int chunk = c * 256 + tid;
            int r = chunk >> 2, slot = chunk & 3;
            int gr = rowBase + r;
            short8 t = {};
            if (gr < M) {
                const float* src = A + (size_t)gr * lda + k0 + slot * 8;
                float4v v0 = *reinterpret_cast<const float4v*>(src);
                float4v v1 = *reinterpret_cast<const float4v*>(src + 4);
                t[0] = (short)f2bf(v0[0]); t[1] = (short)f2bf(v0[1]);
                t[2] = (short)f2bf(v0[2]); t[3] = (short)f2bf(v0[3]);
                t[4] = (short)f2bf(v1[0]); t[5] = (short)f2bf(v1[1]);
                t[6] = (short)f2bf(v1[2]); t[7] = (short)f2bf(v1[3]);
            }
            int sslot = slot ^ (r & 3);
            *reinterpret_cast<short8*>(&As[r * 32 + sslot * 8]) = t;
        }
#pragma unroll
        for (int c = 0; c < 2; ++c) {
            int chunk = c * 256 + tid;
            int r = chunk >> 2, slot = chunk & 3;
            int gn = colBase + r;
            short8 t = {};
            if (gn < N)
                t = *reinterpret_cast<const short8*>(Bt + (size_t)gn * ldb + k0 + slot * 8);
            int sslot = slot ^ (r & 3);
            *reinterpret_cast<short8*>(&Bs[r * 32 + sslot * 8]) = t;
        }
        __syncthreads();

        short8 af[4], bfr[4];
#pragma unroll
        for (int m = 0; m < 4; ++m) {
            int r = wr + m * 16 + r16;
            af[m] = *reinterpret_cast<const short8*>(&As[r * 32 + (g ^ (r & 3)) * 8]);
        }
#pragma unroll
        for (int n = 0; n < 4; ++n) {
            int r = wc + n * 16 + r16;
            bfr[n] = *reinterpret_cast<const short8*>(&Bs[r * 32 + (g ^ (r & 3)) * 8]);
        }
#pragma unroll
        for (int m = 0; m < 4; ++m)
#pragma unroll
            for (int n = 0; n < 4; ++n)
                acc[m][n] = __builtin_amdgcn_mfma_f32_16x16x32_bf16(
                    af[m], bfr[n], acc[m][n], 0, 0, 0);
        __syncthreads();
    }

#pragma unroll
    for (int m = 0; m < 4; ++m) {
#pragma unroll
        for (int v = 0; v < 4; ++v) {
            int gr = rowBase + wr + m * 16 + g * 4 + v;
            if (gr >= M) continue;
#pragma unroll
            for (int n = 0; n < 4; ++n) {
                int gc = colBase + wc + n * 16 + r16;
                if (gc >= N) continue;
                float val = acc[m][n][v] + bias[gc];
                if (ACT == 1) val = (val > 20.f) ? val : log1pf(expf(val));
                C[(size_t)gr * ldc + gc] = val;
            }
        }
    }
}

// ---------------- depthwise causal conv (mean of 3) + SiLU -------------------
// MODE 0: write f32 xconv (tier-2). MODE 1: write only bf16 mirror (tier-1;
// the f32 conv is recomputed in-register inside the scan passes).
template <int MODE>
__global__ __launch_bounds__(256) void conv_silu(
    const float* __restrict__ xz, float* __restrict__ xconv,
    unsigned short* __restrict__ xconv_bf)
{
    int idx = blockIdx.x * blockDim.x + threadIdx.x;
    if (idx >= 4096 * 2048) return;
    int d = idx & 2047;
    int row = idx >> 11;        // row = b*2048 + l
    int l = row & 2047;

    float s = xz[(size_t)row * 4096 + d];
    if (l >= 1) s += xz[(size_t)(row - 1) * 4096 + d];
    if (l >= 2) s += xz[(size_t)(row - 2) * 4096 + d];
    s *= (1.f / 3.f);
    float sv = s / (1.f + __expf(-s));
    if (MODE == 0) xconv[idx] = sv;
    else           xconv_bf[idx] = f2bf(sv);
}

// ---------------- chunked selective scan, 4-states-per-lane, fused conv ------
// Lane: chi = lane&15 (channel), ng = lane>>4 (state quad). Block covers 64
// channels x CT timesteps. Grid: 2048 = b(2) x c(32) x dg(32).
// x_conv is recomputed from xz with a 2-register sliding window (identical
// math to conv_silu, so results match the unfused pipeline bit-for-bit).

// Pass A: per chunk with h_in = 0: P = prod(dA) (x4), S = local final state.
__global__ __launch_bounds__(256) void scan_passA(
    const float* __restrict__ dt,     // [4096][2048]
    const float* __restrict__ xdbl,   // [4096][96]
    const float* __restrict__ xz,     // [4096][4096] (x_inner at cols 0..2047)
    const float* __restrict__ A_log,  // [2048][16]
    float* __restrict__ Pc,           // [2][32][2048][16]
    float* __restrict__ Sc)           // [2][32][2048][16]
{
    __shared__ float sB[CT][16];
    const int tid  = threadIdx.x;
    const int bid  = blockIdx.x;
    const int dg   = bid & 31;
    const int c    = (bid >> 5) & 31;
    const int b    = bid >> 10;
    const int lane = tid & 63;
    const int wave = tid >> 6;
    const int chi  = lane & 15;
    const int ng   = lane >> 4;          // 0..3
    const int d    = dg * 64 + wave * 16 + chi;
    const size_t rowBase = (size_t)b * 2048 + (size_t)c * CT;

    for (int i = tid; i < CT * 4; i += 256) {
        int tt = i >> 2, q = i & 3;
        *reinterpret_cast<float4v*>(&sB[tt][q * 4]) =
            *reinterpret_cast<const float4v*>(&xdbl[(rowBase + tt) * 96 + 64 + q * 4]);
    }
    __syncthreads();

    float4v Aval, h = {}, P = {1.f, 1.f, 1.f, 1.f};
#pragma unroll
    for (int j = 0; j < 4; ++j) Aval[j] = -expf(A_log[d * 16 + ng * 4 + j]);

    const float* pdt = dt + rowBase * 2048 + d;
    const float* pxz = xz + rowBase * 4096 + d;
    float w2 = 0.f, w1 = 0.f;
    if (c > 0) { w2 = pxz[-2 * 4096]; w1 = pxz[-4096]; }   // l0 = c*CT >= 2
    float dt_c = *pdt, curx = *pxz;

    for (int t = 0; t < CT; ++t) {
        float dt_n = 0.f, cur_n = 0.f;
        if (t + 1 < CT) { dt_n = pdt[2048]; cur_n = pxz[4096]; }
        pdt += 2048; pxz += 4096;

        float s = (w2 + w1 + curx) * (1.f / 3.f);
        float x_c = s / (1.f + __expf(-s));

        float4v Bv = *reinterpret_cast<const float4v*>(&sB[t][ng * 4]);
        float u = dt_c * x_c;
#pragma unroll
        for (int j = 0; j < 4; ++j) {
            float dA = __expf(Aval[j] * dt_c);
            P[j] *= dA;
            h[j] = dA * h[j] + u * Bv[j];
        }
        w2 = w1; w1 = curx; curx = cur_n; dt_c = dt_n;
    }
    size_t o = (((size_t)(b * NCHUNK + c)) * 2048 + d) * 16 + ng * 4;
    *reinterpret_cast<float4v*>(&Pc[o]) = P;
    *reinterpret_cast<float4v*>(&Sc[o]) = h;
}

// Pass B: sequential over chunks, in place: Pc[c] <- state at START of chunk c.
__global__ __launch_bounds__(256) void scan_passB(
    float* __restrict__ Pc, const float* __restrict__ Sc)
{
    int idx = blockIdx.x * 256 + threadIdx.x;   // 0..16383
    int ng  = idx & 3;
    int d   = (idx >> 2) & 2047;
    int b   = idx >> 13;
    float4v h = {};
#pragma unroll
    for (int c = 0; c < NCHUNK; ++c) {
        size_t o = (((size_t)(b * NCHUNK + c)) * 2048 + d) * 16 + ng * 4;
        float4v Pv = *reinterpret_cast<const float4v*>(&Pc[o]);
        float4v Sv = *reinterpret_cast<const float4v*>(&Sc[o]);
        *reinterpret_cast<float4v*>(&Pc[o]) = h;
#pragma unroll
        for (int j = 0; j < 4; ++j) h[j] = Pv[j] * h[j] + Sv[j];
    }
}

// Pass C: local rescan seeded with Pc (= chunk-start state after passB);
// fused conv recompute + skip + gate; writes bf16 gated.
__global__ __launch_bounds__(256) void scan_passC2(
    const float* __restrict__ dt,
    const float* __restrict__ xdbl,
    const float* __restrict__ xz,     // x_inner cols 0..2047, z cols 2048..4095
    const float* __restrict__ A_log,
    const float* __restrict__ Dp,
    const float* __restrict__ Pc,     // start states (post-passB)
    unsigned short* __restrict__ gated_bf)
{
    __shared__ float sBC[CT][32];
    const int tid  = threadIdx.x;
    const int bid  = blockIdx.x;
    const int dg   = bid & 31;
    const int c    = (bid >> 5) & 31;
    const int b    = bid >> 10;
    const int lane = tid & 63;
    const int wave = tid >> 6;
    const int chi  = lane & 15;
    const int ng   = lane >> 4;
    const int d    = dg * 64 + wave * 16 + chi;
    const size_t rowBase = (size_t)b * 2048 + (size_t)c * CT;

    for (int i = tid; i < CT * 8; i += 256) {
        int tt = i >> 3, q = i & 7;
        *reinterpret_cast<float4v*>(&sBC[tt][q * 4]) =
            *reinterpret_cast<const float4v*>(&xdbl[(rowBase + tt) * 96 + 64 + q * 4]);
    }
    __syncthreads();

    float4v Aval;
#pragma unroll
    for (int j = 0; j < 4; ++j) Aval[j] = -expf(A_log[d * 16 + ng * 4 + j]);
    const float Dval = Dp[d];

    float4v h = *reinterpret_cast<const float4v*>(
        &Pc[(((size_t)(b * NCHUNK + c)) * 2048 + d) * 16 + ng * 4]);

    const float* pdt = dt + rowBase * 2048 + d;
    const float* pxz = xz + rowBase * 4096 + d;
    const float* pz  = xz + rowBase * 4096 + 2048 + d;
    unsigned short* pwb = gated_bf + rowBase * 2048 + d;
    float w2 = 0.f, w1 = 0.f;
    if (c > 0) { w2 = pxz[-2 * 4096]; w1 = pxz[-4096]; }
    float dt_c = *pdt, curx = *pxz;

    for (int t = 0; t < CT; ++t) {
        float dt_n = 0.f, cur_n = 0.f;
        if (t + 1 < CT) { dt_n = pdt[2048]; cur_n = pxz[4096]; }
        pdt += 2048; pxz += 4096;

        float s = (w2 + w1 + curx) * (1.f / 3.f);
        float x_c = s / (1.f + __expf(-s));

        float4v Bv = *reinterpret_cast<const float4v*>(&sBC[t][ng * 4]);
        float4v Cv = *reinterpret_cast<const float4v*>(&sBC[t][16 + ng * 4]);
        float u = dt_c * x_c;
        float p = 0.f;
#pragma unroll
        for (int j = 0; j < 4; ++j) {
            float dA = __expf(Aval[j] * dt_c);
            h[j] = dA * h[j] + u * Bv[j];
            p += h[j] * Cv[j];
        }
        p += __shfl_xor(p, 16);
        p += __shfl_xor(p, 32);

        if (ng == 0) {
            float y = p + x_c * Dval;
            float zv = *pz;
            float sz = zv / (1.f + __expf(-zv));
            *pwb = f2bf(y * sz);
        }
        pz += 4096; pwb += 2048;
        w2 = w1; w1 = curx; curx = cur_n; dt_c = dt_n;
    }
}

// ---------------- monolithic scan (tier-2 fallback; round-4 proven) ----------
__global__ __launch_bounds__(256) void scan_kernel(
    const float* __restrict__ dt, const float* __restrict__ xdbl,
    const float* __restrict__ xz, float* __restrict__ xconv,
    const float* __restrict__ A_log, const float* __restrict__ Dp)
{
    const int L = 2048, DI = 2048;
    const int n = threadIdx.x & 15;
    const int chi = threadIdx.x >> 4;
    const int b = blockIdx.x / 128;
    const int d = (blockIdx.x % 128) * 16 + chi;

    const float Aval = -expf(A_log[d * 16 + n]);
    const float Dval = Dp[d];
    float h = 0.f;
    const size_t rowBase = (size_t)b * L;

    float dt_c = dt[rowBase * DI + d];
    float x_c  = xconv[rowBase * DI + d];
    float B_c  = xdbl[rowBase * 96 + 64 + n];
    float C_c  = xdbl[rowBase * 96 + 80 + n];

    for (int t = 0; t < L; ++t) {
        size_t row = rowBase + t;
        float dt_n = 0.f, x_n = 0.f, B_n = 0.f, C_n = 0.f;
        if (t + 1 < L) {
            size_t rn = row + 1;
            dt_n = dt[rn * DI + d];
            x_n  = xconv[rn * DI + d];
            B_n  = xdbl[rn * 96 + 64 + n];
            C_n  = xdbl[rn * 96 + 80 + n];
        }
        float dA = __expf(Aval * dt_c);
        h = dA * h + (dt_c * x_c) * B_c;
        float p = h * C_c;
        p += __shfl_xor(p, 1, 16);
        p += __shfl_xor(p, 2, 16);
        p += __shfl_xor(p, 4, 16);
        p += __shfl_xor(p, 8, 16);
        if (n == 0) {
            float y = p + x_c * Dval;
            float zv = xz[row * 4096 + 2048 + d];
            float sz = zv / (1.f + __expf(-zv));
            xconv[row * DI + d] = y * sz;
        }
        dt_c = dt_n; x_c = x_n; B_c = B_n; C_c = C_n;
    }
}

extern "C" void kernel_launch(void* const* d_in, const int* in_sizes, int n_in,
                              void* d_out, int out_size, void* d_ws, size_t ws_size,
                              hipStream_t stream)
{
    const float* x     = (const float*)d_in[0];
    const float* W_in  = (const float*)d_in[1];
    const float* b_in  = (const float*)d_in[2];
    const float* W_x   = (const float*)d_in[3];
    const float* b_x   = (const float*)d_in[4];
    const float* W_dt  = (const float*)d_in[5];
    const float* b_dt  = (const float*)d_in[6];
    const float* A_log = (const float*)d_in[7];
    const float* Dp    = (const float*)d_in[8];
    const float* W_out = (const float*)d_in[9];
    const float* b_out = (const float*)d_in[10];
    float* out = (float*)d_out;

    float* ws    = (float*)d_ws;
    float* xz    = ws;                       // 16,777,216 f32
    float* xconv = xz + 16777216;            //  8,388,608 f32 (tier-2 only)
    float* xdbl  = xconv + 8388608;          //    393,216 f32
    float* dtbuf = xdbl + 393216;            //  8,388,608 f32
    float* Pc    = dtbuf + 8388608;          //  2,097,152 f32
    float* Sc    = Pc + 2097152;             //  2,097,152 f32
    float* Cpart = Sc + 2097152;             //  1,572,864 f32 (4 x 4096 x 96)

    const size_t base_f32 = 16777216 + 8388608 + 393216 + 8388608;   // floats
    const size_t wshorts  = 4096 * 1024 + 96 * 2048 + 2048 * 64 + 1024 * 2048;
    const size_t bfshorts = 4096 * 1024 + 8388608 + 4096 * 64;  // x, xconv(=gated), xdbl
    const size_t needed_t1 = (base_f32 + 2 * 2097152 + 1572864) * 4
                           + (wshorts + bfshorts) * 2;          // 197,787,648
    const size_t needed_t2 = base_f32 * 4 + wshorts * 2;        // 149,028,864

    const int tier = (ws_size >= needed_t1) ? 1 : (ws_size >= needed_t2) ? 2 : 0;
    if (tier == 0) return;   // tripwire: clean fail, never corrupt memory

    unsigned short* wbuf = (tier == 1) ? (unsigned short*)(Cpart + 1572864)
                                       : (unsigned short*)Pc;
    unsigned short* WinT  = wbuf;                  // [4096][1024] bf16
    unsigned short* WxT   = WinT  + 4096 * 1024;   // [96][2048]
    unsigned short* WdtT  = WxT   + 96 * 2048;     // [2048][64]
    unsigned short* WoutT = WdtT  + 2048 * 64;     // [1024][2048]
    // tier-1 bf16 mirrors; gated_bf aliases xconv_bf (GEMM3 done before passC2)
    unsigned short* x_bf     = WoutT + 1024 * 2048;   // [4096][1024]
    unsigned short* xconv_bf = x_bf + 4096 * 1024;    // [4096][2048]
    unsigned short* xdbl_bf  = xconv_bf + 8388608;    // [4096][64]
    unsigned short* gated_bf = xconv_bf;              // alias (safe: see order)

    dim3 tblk(32, 8);
    transpose_bf16<<<dim3(128, 32), tblk, 0, stream>>>(W_in, WinT, 1024, 4096);
    transpose_bf16<<<dim3(3, 64),   tblk, 0, stream>>>(W_x,  WxT,  2048, 96);
    transpose_bf16<<<dim3(64, 2),   tblk, 0, stream>>>(W_dt, WdtT, 64, 2048);
    transpose_bf16<<<dim3(32, 64),  tblk, 0, stream>>>(W_out,WoutT,2048, 1024);

    dim3 blk(256);

    if (tier == 1) {
        // 0) x -> bf16
        cast_bf16<<<2048, blk, 0, stream>>>(x, x_bf, 4096 * 1024 / 8);

        // 1) xz = x @ W_in + b_in   (M=4096, N=4096, K=1024)
        gemm_bf<0, false><<<dim3(32, 32), blk, 0, stream>>>(
            x_bf, 1024, WinT, 1024, b_in, xz, 4096, 4096, 1024, 0);

        // 2) bf16 mirror of x_conv (GEMM3 input); f32 conv fused into scan
        conv_silu<1><<<(4096 * 2048 + 255) / 256, blk, 0, stream>>>(
            xz, nullptr, xconv_bf);

        // 3) x_dbl partials: split-K=4 over K=2048 (grid x = split index)
        gemm_bf<0, true><<<dim3(4, 32), blk, 0, stream>>>(
            xconv_bf, 2048, WxT, 2048, nullptr, Cpart, 96, 96, 512,
            (size_t)4096 * 96);
        combine3<<<1536, blk, 0, stream>>>(Cpart, b_x, xdbl, xdbl_bf);

        // 4) dt = softplus(x_dbl[:, :64] @ W_dt + b_dt)   (N=2048, K=64)
        gemm_bf<1, false><<<dim3(16, 32), blk, 0, stream>>>(
            xdbl_bf, 64, WdtT, 64, b_dt, dtbuf, 2048, 2048, 64, 0);

        // 5) chunked scan (conv fused): A (local), B (prefix), C (rescan+gate)
        scan_passA<<<2048, blk, 0, stream>>>(dtbuf, xdbl, xz, A_log, Pc, Sc);
        scan_passB<<<64, blk, 0, stream>>>(Pc, Sc);
        scan_passC2<<<2048, blk, 0, stream>>>(
            dtbuf, xdbl, xz, A_log, Dp, Pc, gated_bf);

        // 6) out = gated @ W_out + b_out   (N=1024, K=2048)
        gemm_bf<0, false><<<dim3(8, 32), blk, 0, stream>>>(
            gated_bf, 2048, WoutT, 2048, b_out, out, 1024, 1024, 2048, 0);
    } else {
        // tier-2: f32-A GEMMs + monolithic scan (proven standalone)
        gemm_mfma<0><<<dim3(32, 32), blk, 0, stream>>>(
            x, 1024, WinT, 1024, b_in, xz, 4096, 4096, 4096, 1024);
        conv_silu<0><<<(4096 * 2048 + 255) / 256, blk, 0, stream>>>(
            xz, xconv, nullptr);
        gemm_mfma<0><<<dim3(1, 32), blk, 0, stream>>>(
            xconv, 2048, WxT, 2048, b_x, xdbl, 96, 4096, 96, 2048);
        gemm_mfma<1><<<dim3(16, 32), blk, 0, stream>>>(
            xdbl, 96, WdtT, 64, b_dt, dtbuf, 2048, 4096, 2048, 64);
        scan_kernel<<<256, blk, 0, stream>>>(dtbuf, xdbl, xz, xconv, A_log, Dp);
        gemm_mfma<0><<<dim3(8, 32), blk, 0, stream>>>(
            xconv, 2048, WoutT, 2048, b_out, out, 1024, 4096, 1024, 2048);
    }
}